// Round 1
// baseline (998.704 us; speedup 1.0000x reference)
//
#include <hip/hip_runtime.h>
#include <hip/hip_bf16.h>

#define N_TLS 16384
#define LMAX_ 16
#define E_ 128
#define P_ 128
#define F_ 256
#define HEADS_ 8
#define DH_ 16
#define RD_ 32

__global__ __launch_bounds__(256) void lane_ppo_fused(
    const float* __restrict__ queues, const float* __restrict__ waits,
    const float* __restrict__ phase_onehot, const float* __restrict__ elapsed,
    const int* __restrict__ lane_counts, const int* __restrict__ region_ids,
    const float* __restrict__ W1, const float* __restrict__ b1,
    const float* __restrict__ W2, const float* __restrict__ b2,
    const float* __restrict__ Wq, const float* __restrict__ bq,
    const float* __restrict__ Wk, const float* __restrict__ bk,
    const float* __restrict__ Wv, const float* __restrict__ bv,
    const float* __restrict__ Wo, const float* __restrict__ bo,
    const float* __restrict__ Wp1, const float* __restrict__ bp1,
    const float* __restrict__ Wp2, const float* __restrict__ bp2,
    const float* __restrict__ region_table,
    const float* __restrict__ Wf1, const float* __restrict__ bf1,
    const float* __restrict__ Wf2, const float* __restrict__ bf2,
    const float* __restrict__ Wm, const float* __restrict__ bm,
    const float* __restrict__ Wval, const float* __restrict__ bval,
    const float* __restrict__ log_std,
    float* __restrict__ out)
{
    const int n = blockIdx.x;
    const int tid = threadIdx.x;

    __shared__ float s_h1[LMAX_ * E_];   // lane-MLP hidden; reused as ctx
    __shared__ float s_emb[LMAX_ * E_];  // lane_emb
    __shared__ float s_q[LMAX_ * E_];
    __shared__ float s_k[LMAX_ * E_];
    __shared__ float s_v[LMAX_ * E_];
    __shared__ float s_qw[2 * LMAX_];
    __shared__ float s_mean[E_];
    __shared__ float s_fused[E_ + P_ + RD_];
    __shared__ float s_ph1[P_];
    __shared__ float s_hf[F_];
    __shared__ float s_hh[F_];
    __shared__ float s_red[16];

    const int L = lane_counts[n];
    const float ev = elapsed[n];

    if (tid < LMAX_)          s_qw[tid] = queues[n * LMAX_ + tid];
    else if (tid < 2 * LMAX_) s_qw[tid] = waits[n * LMAX_ + (tid - LMAX_)];
    __syncthreads();

    // ---- Stage A: h1 = relu(lane_feats @ W1 + b1), only rows l < L
    for (int idx = tid; idx < L * E_; idx += 256) {
        int l = idx >> 7, j = idx & 127;
        float acc = fmaf(s_qw[l], W1[j],
                    fmaf(s_qw[LMAX_ + l], W1[E_ + j],
                    fmaf(ev, W1[2 * E_ + j], b1[j])));
        s_h1[idx] = fmaxf(acc, 0.f);
    }
    __syncthreads();

    const int j = tid & 127;
    const int half = tid >> 7;  // wave-uniform: waves 0,1 -> half 0; waves 2,3 -> half 1

    // ---- Stage B: emb = relu(h1 @ W2 + b2). Thread (j,half) owns rows l = half+2u.
    // Always compute 8 accumulators (garbage for invalid rows, never stored).
    {
        float acc[8];
        #pragma unroll
        for (int u = 0; u < 8; ++u) acc[u] = b2[j];
        for (int k = 0; k < E_; ++k) {
            float w = W2[k * E_ + j];
            #pragma unroll
            for (int u = 0; u < 8; ++u)
                acc[u] = fmaf(s_h1[(half + 2 * u) * E_ + k], w, acc[u]);
        }
        #pragma unroll
        for (int u = 0; u < 8; ++u) {
            int l = half + 2 * u;
            if (l < L) s_emb[l * E_ + j] = fmaxf(acc[u], 0.f);
        }
    }
    __syncthreads();

    // ---- Stage C: q,k,v = emb @ W{q,k,v} + b. Zero-fill invalid k,v rows.
    {
        float aq[8], ak[8], av[8];
        #pragma unroll
        for (int u = 0; u < 8; ++u) { aq[u] = bq[j]; ak[u] = bk[j]; av[u] = bv[j]; }
        for (int k = 0; k < E_; ++k) {
            float wq = Wq[k * E_ + j];
            float wk = Wk[k * E_ + j];
            float wv = Wv[k * E_ + j];
            #pragma unroll
            for (int u = 0; u < 8; ++u) {
                float x = s_emb[(half + 2 * u) * E_ + k];
                aq[u] = fmaf(x, wq, aq[u]);
                ak[u] = fmaf(x, wk, ak[u]);
                av[u] = fmaf(x, wv, av[u]);
            }
        }
        #pragma unroll
        for (int u = 0; u < 8; ++u) {
            int l = half + 2 * u;
            bool valid = (l < L);
            if (valid) s_q[l * E_ + j] = aq[u];
            s_k[l * E_ + j] = valid ? ak[u] : 0.f;
            s_v[l * E_ + j] = valid ? av[u] : 0.f;
        }
    }
    __syncthreads();

    // ---- Stage D: attention per (head h, query row i<L). ctx -> s_h1 (reuse).
    if (tid < HEADS_ * LMAX_) {
        int i = tid & 15;
        int h = tid >> 4;
        if (i < L) {
            float qr[DH_];
            #pragma unroll
            for (int d = 0; d < DH_; ++d) qr[d] = s_q[i * E_ + h * DH_ + d];
            float sc[LMAX_];
            float m = -1e30f;
            #pragma unroll
            for (int jj = 0; jj < LMAX_; ++jj) {
                float a = 0.f;
                #pragma unroll
                for (int d = 0; d < DH_; ++d)
                    a = fmaf(qr[d], s_k[jj * E_ + h * DH_ + d], a);
                sc[jj] = a * 0.25f;  // 1/sqrt(16)
                if (jj < L) m = fmaxf(m, sc[jj]);
            }
            float psum = 0.f;
            #pragma unroll
            for (int jj = 0; jj < LMAX_; ++jj) {
                float p = (jj < L) ? __expf(sc[jj] - m) : 0.f;
                sc[jj] = p;
                psum += p;
            }
            float inv = 1.f / psum;
            #pragma unroll
            for (int d = 0; d < DH_; ++d) {
                float a = 0.f;
                #pragma unroll
                for (int jj = 0; jj < LMAX_; ++jj)
                    a = fmaf(sc[jj], s_v[jj * E_ + h * DH_ + d], a);
                s_h1[i * E_ + h * DH_ + d] = a * inv;
            }
        }
    }
    __syncthreads();

    // ---- Stage E: masked mean over lanes (mean commutes with the Wo linear)
    if (tid < E_) {
        float a = 0.f;
        for (int l = 0; l < L; ++l) a += s_h1[l * E_ + tid];
        s_mean[tid] = a / (float)L;
    }
    __syncthreads();

    // ---- Stage F (threads 0..127): lane_context = mean @ Wo + bo
    // ---- Stage G1 (threads 128..255): phase hidden
    if (tid < E_) {
        float a = bo[tid];
        for (int k = 0; k < E_; ++k) a = fmaf(s_mean[k], Wo[k * E_ + tid], a);
        s_fused[tid] = a;
    } else {
        int jj = tid - 128;
        float a = fmaf(phase_onehot[n * 4 + 0], Wp1[0 * P_ + jj],
                  fmaf(phase_onehot[n * 4 + 1], Wp1[1 * P_ + jj],
                  fmaf(phase_onehot[n * 4 + 2], Wp1[2 * P_ + jj],
                  fmaf(phase_onehot[n * 4 + 3], Wp1[3 * P_ + jj],
                  fmaf(ev, Wp1[4 * P_ + jj], bp1[jj])))));
        s_ph1[jj] = fmaxf(a, 0.f);
    }
    __syncthreads();

    // ---- Stage G2: phase_emb -> s_fused[128:256]; region emb -> s_fused[256:288]
    if (tid < P_) {
        float a = bp2[tid];
        for (int k = 0; k < P_; ++k) a = fmaf(s_ph1[k], Wp2[k * P_ + tid], a);
        s_fused[E_ + tid] = fmaxf(a, 0.f);
    } else if (tid < P_ + RD_) {
        int r = tid - P_;
        s_fused[E_ + P_ + r] = region_table[region_ids[n] * RD_ + r];
    }
    __syncthreads();

    // ---- Stage H: hf = relu(fused @ Wf1 + bf1), 256 outputs, one per thread
    {
        float a = bf1[tid];
        for (int k = 0; k < E_ + P_ + RD_; ++k)
            a = fmaf(s_fused[k], Wf1[k * F_ + tid], a);
        s_hf[tid] = fmaxf(a, 0.f);
    }
    __syncthreads();

    // ---- Stage I: h = relu(hf @ Wf2 + bf2)
    {
        float a = bf2[tid];
        for (int k = 0; k < F_; ++k) a = fmaf(s_hf[k], Wf2[k * F_ + tid], a);
        s_hh[tid] = fmaxf(a, 0.f);
    }
    __syncthreads();

    // ---- Stage J: scalar heads + block reduce
    {
        float hm = s_hh[tid] * Wm[tid];
        float hv = s_hh[tid] * Wval[tid];
        #pragma unroll
        for (int off = 32; off > 0; off >>= 1) {
            hm += __shfl_down(hm, off, 64);
            hv += __shfl_down(hv, off, 64);
        }
        int wave = tid >> 6;
        if ((tid & 63) == 0) { s_red[wave] = hm; s_red[8 + wave] = hv; }
    }
    __syncthreads();
    if (tid == 0) {
        float m0 = s_red[0] + s_red[1] + s_red[2] + s_red[3] + bm[0];
        float v0 = s_red[8] + s_red[9] + s_red[10] + s_red[11] + bval[0];
        out[n] = m0;
        out[N_TLS + n] = log_std[0];
        out[2 * N_TLS + n] = v0;
    }
}

extern "C" void kernel_launch(void* const* d_in, const int* in_sizes, int n_in,
                              void* d_out, int out_size, void* d_ws, size_t ws_size,
                              hipStream_t stream) {
    const float* queues       = (const float*)d_in[0];
    const float* waits        = (const float*)d_in[1];
    const float* phase_onehot = (const float*)d_in[2];
    const float* elapsed      = (const float*)d_in[3];
    const int*   lane_counts  = (const int*)d_in[4];
    const int*   region_ids   = (const int*)d_in[5];
    const float* W1  = (const float*)d_in[6];
    const float* b1  = (const float*)d_in[7];
    const float* W2  = (const float*)d_in[8];
    const float* b2  = (const float*)d_in[9];
    const float* Wq  = (const float*)d_in[10];
    const float* bq  = (const float*)d_in[11];
    const float* Wk  = (const float*)d_in[12];
    const float* bk  = (const float*)d_in[13];
    const float* Wv  = (const float*)d_in[14];
    const float* bv  = (const float*)d_in[15];
    const float* Wo  = (const float*)d_in[16];
    const float* bo  = (const float*)d_in[17];
    const float* Wp1 = (const float*)d_in[18];
    const float* bp1 = (const float*)d_in[19];
    const float* Wp2 = (const float*)d_in[20];
    const float* bp2 = (const float*)d_in[21];
    const float* region_table = (const float*)d_in[22];
    const float* Wf1 = (const float*)d_in[23];
    const float* bf1 = (const float*)d_in[24];
    const float* Wf2 = (const float*)d_in[25];
    const float* bf2 = (const float*)d_in[26];
    const float* Wm  = (const float*)d_in[27];
    const float* bm  = (const float*)d_in[28];
    const float* Wval = (const float*)d_in[29];
    const float* bval = (const float*)d_in[30];
    const float* log_std = (const float*)d_in[31];
    float* out = (float*)d_out;

    lane_ppo_fused<<<N_TLS, 256, 0, stream>>>(
        queues, waits, phase_onehot, elapsed, lane_counts, region_ids,
        W1, b1, W2, b2, Wq, bq, Wk, bk, Wv, bv, Wo, bo,
        Wp1, bp1, Wp2, bp2, region_table, Wf1, bf1, Wf2, bf2,
        Wm, bm, Wval, bval, log_std, out);
}

// Round 2
// 277.962 us; speedup vs baseline: 3.5929x; 3.5929x over previous
//
#include <hip/hip_runtime.h>
#include <hip/hip_bf16.h>
#include <stdint.h>

#define NTLS 16384

typedef float f32x4 __attribute__((ext_vector_type(4)));
typedef short bf16x8 __attribute__((ext_vector_type(8)));
typedef short bf16x4 __attribute__((ext_vector_type(4)));

__device__ __forceinline__ short f2bf(float x){
    union { float f; unsigned u; } v; v.f = x;
    unsigned r = (v.u + 0x7FFFu + ((v.u >> 16) & 1u)) >> 16;
    return (short)r;
}
__device__ __forceinline__ float bf2f(short s){
    union { float f; unsigned u; } v; v.u = ((unsigned)(unsigned short)s) << 16; return v.f;
}
__device__ __forceinline__ unsigned pk2(float a, float b){
    return ((unsigned)(unsigned short)f2bf(a)) | (((unsigned)(unsigned short)f2bf(b)) << 16);
}
__device__ __forceinline__ unsigned lds_lo(const void* p){
    return (unsigned)(size_t)p;
}
__device__ __forceinline__ bf16x4 ds_tr(unsigned addr){
    bf16x4 d;
    asm volatile("ds_read_b64_tr_b16 %0, %1" : "=v"(d) : "v"(addr) : "memory");
    return d;
}
__device__ __forceinline__ void lgkm0(){
    asm volatile("s_waitcnt lgkmcnt(0)" ::: "memory");
    __builtin_amdgcn_sched_barrier(0);
}
__device__ __forceinline__ bf16x8 cat44(bf16x4 lo, bf16x4 hi){
    bf16x8 r;
    r[0]=lo[0]; r[1]=lo[1]; r[2]=lo[2]; r[3]=lo[3];
    r[4]=hi[0]; r[5]=hi[1]; r[6]=hi[2]; r[7]=hi[3];
    return r;
}
__device__ __forceinline__ bf16x8 cat40(bf16x4 lo){
    bf16x8 r;
    r[0]=lo[0]; r[1]=lo[1]; r[2]=lo[2]; r[3]=lo[3];
    r[4]=0; r[5]=0; r[6]=0; r[7]=0;
    return r;
}
#define MFMA16(a,b,c) __builtin_amdgcn_mfma_f32_16x16x32_bf16((a),(b),(c),0,0,0)

// ---------------- weight prepack: fp32 row-major -> bf16 fragment-linear ----------------
// frag layout for W[K][N]: frag f = nt*KT + kt, 64 lanes x 8 bf16 (16B/lane).
// lane slot s<4  -> W[kt*32 + 4*(l>>4) + s      ][nt*16 + (l&15)]
// lane slot s>=4 -> W[kt*32 + 16 + 4*(l>>4)+s-4 ][nt*16 + (l&15)]
// (sigma matches the k-order delivered by two ds_read_b64_tr_b16 on col-major LDS)
__global__ __launch_bounds__(256) void prepack(
    const float* __restrict__ W2, const float* __restrict__ Wq,
    const float* __restrict__ Wk, const float* __restrict__ Wv,
    const float* __restrict__ Wo, const float* __restrict__ Wp2,
    const float* __restrict__ Wf1, const float* __restrict__ Wf2,
    short* __restrict__ out)
{
    int gid = blockIdx.x * 256 + threadIdx.x;      // 0..29695
    const float* src; short* dst; int K, Nn; int id = gid;
    if (id < 12288){
        int wsel = id >> 11; id &= 2047;
        const float* tab[6] = {W2, Wq, Wk, Wv, Wo, Wp2};
        src = tab[wsel]; dst = out + wsel * 16384; K = 128; Nn = 128;
    } else if (id < 21504){
        id -= 12288; src = Wf1; dst = out + 98304; K = 288; Nn = 256;
    } else {
        id -= 21504; src = Wf2; dst = out + 172032; K = 256; Nn = 256;
    }
    int lane = id & 63, f = id >> 6;
    int KT = K >> 5;
    int nt = f / KT, kt = f - nt * KT;
    int n  = nt * 16 + (lane & 15);
    int kb = kt * 32 + 4 * (lane >> 4);
    unsigned w0 = pk2(src[(kb+0)*Nn+n],  src[(kb+1)*Nn+n]);
    unsigned w1 = pk2(src[(kb+2)*Nn+n],  src[(kb+3)*Nn+n]);
    unsigned w2 = pk2(src[(kb+16)*Nn+n], src[(kb+17)*Nn+n]);
    unsigned w3 = pk2(src[(kb+18)*Nn+n], src[(kb+19)*Nn+n]);
    *(uint4*)&dst[(f*64+lane)*8] = make_uint4(w0,w1,w2,w3);
}

// ---------------- fused policy kernel: 4 TLS / block, 1 TLS / wave ----------------
__global__ __launch_bounds__(256, 2) void lane_ppo_mfma(
    const float* __restrict__ queues, const float* __restrict__ waits,
    const float* __restrict__ phase_onehot, const float* __restrict__ elapsed,
    const int* __restrict__ lane_counts, const int* __restrict__ region_ids,
    const float* __restrict__ W1, const float* __restrict__ b1,
    const float* __restrict__ b2,
    const float* __restrict__ bq, const float* __restrict__ bk_, const float* __restrict__ bv_,
    const float* __restrict__ bo,
    const float* __restrict__ Wp1, const float* __restrict__ bp1, const float* __restrict__ bp2,
    const float* __restrict__ region_table,
    const float* __restrict__ bf1, const float* __restrict__ bf2_,
    const float* __restrict__ Wm, const float* __restrict__ bm,
    const float* __restrict__ Wval, const float* __restrict__ bval,
    const float* __restrict__ log_std,
    const short* __restrict__ wpk,
    float* __restrict__ out)
{
    const int tid  = threadIdx.x;
    const int w    = tid >> 6, lane = tid & 63;
    const int nl   = lane & 15, kb = lane >> 4;
    const int base = blockIdx.x << 2;
    const int n    = base + w;

    // per-wave activation buffers (bf16 col-major [col][16]): h1/q, emb, k, v (2048 each)
    __shared__ __align__(16) short s_act[4][8192];
    __shared__ __align__(16) short s_fused[288*16];   // [lane_ctx|phase|region] col-major
    __shared__ __align__(16) short s_ph1[128*16];

    short* h1   = &s_act[w][0];
    short* embb = &s_act[w][2048];
    short* kbuf = &s_act[w][4096];
    short* vbuf = &s_act[w][6144];
    short* qbuf = h1;                     // q overwrites h1 (dead after stage B)
    short* hf   = &s_act[0][0];           // tail alias: fusion hidden 1 (256*16)
    short* hb   = &s_act[0][4096];        // tail alias: fusion hidden 2 (256*16)

    const bf16x8* Wpk2  = (const bf16x8*)(wpk);
    const bf16x8* WpkQ  = (const bf16x8*)(wpk + 16384);
    const bf16x8* WpkK  = (const bf16x8*)(wpk + 32768);
    const bf16x8* WpkV  = (const bf16x8*)(wpk + 49152);
    const bf16x8* WpkO  = (const bf16x8*)(wpk + 65536);
    const bf16x8* WpkP2 = (const bf16x8*)(wpk + 81920);
    const bf16x8* WpkF1 = (const bf16x8*)(wpk + 98304);
    const bf16x8* WpkF2 = (const bf16x8*)(wpk + 172032);

    // ---- step 1: phase-MLP hidden + region embedding (independent of lane pipeline)
    {
        int c = tid & 127, r0 = tid >> 7;
        float p0 = Wp1[c], p1 = Wp1[128+c], p2 = Wp1[256+c], p3 = Wp1[384+c], p4 = Wp1[512+c];
        float bb = bp1[c];
        #pragma unroll
        for (int rr = 0; rr < 2; ++rr){
            int r = r0 + 2*rr, nn = base + r;
            float a = fmaf(phase_onehot[nn*4+0], p0,
                      fmaf(phase_onehot[nn*4+1], p1,
                      fmaf(phase_onehot[nn*4+2], p2,
                      fmaf(phase_onehot[nn*4+3], p3,
                      fmaf(elapsed[nn], p4, bb)))));
            s_ph1[c*16 + r] = f2bf(fmaxf(a, 0.f));
        }
        if (tid < 128){
            int r = tid >> 5, cc = tid & 31;
            s_fused[(256+cc)*16 + r] = f2bf(region_table[region_ids[base+r]*32 + cc]);
        }
    }

    const int   L    = lane_counts[n];
    const float ev   = elapsed[n];
    const float invL = 1.f / (float)L;
    const unsigned trofs = (unsigned)(kb*128 + nl*8);   // lane-linear tr-read offset

    // ---- stage A: h1 = relu(lane_feats @ W1 + b1), col-major bf16
    {
        float qv = queues[n*16 + nl];
        float wv = waits [n*16 + nl];
        float qm[4], wmv[4];
        #pragma unroll
        for (int r = 0; r < 4; ++r){
            qm[r]  = __shfl(qv, 4*kb + r, 16);
            wmv[r] = __shfl(wv, 4*kb + r, 16);
        }
        #pragma unroll
        for (int i = 0; i < 8; ++i){
            int c = nl + 16*i;
            float w0 = W1[c], w1 = W1[128+c], w2 = W1[256+c], bb = b1[c];
            float v0 = fmaxf(fmaf(qm[0], w0, fmaf(wmv[0], w1, fmaf(ev, w2, bb))), 0.f);
            float v1 = fmaxf(fmaf(qm[1], w0, fmaf(wmv[1], w1, fmaf(ev, w2, bb))), 0.f);
            float v2 = fmaxf(fmaf(qm[2], w0, fmaf(wmv[2], w1, fmaf(ev, w2, bb))), 0.f);
            float v3 = fmaxf(fmaf(qm[3], w0, fmaf(wmv[3], w1, fmaf(ev, w2, bb))), 0.f);
            *(uint2*)&h1[c*16 + 4*kb] = make_uint2(pk2(v0,v1), pk2(v2,v3));
        }
    }

    // ---- stage B: emb = relu(h1 @ W2 + b2)   [M=16,K=128,N=128]
    {
        unsigned ab = lds_lo(h1) + trofs;
        bf16x4 t[8];
        #pragma unroll
        for (int kt = 0; kt < 4; ++kt){
            t[2*kt]   = ds_tr(ab + kt*1024);
            t[2*kt+1] = ds_tr(ab + kt*1024 + 512);
        }
        lgkm0();
        bf16x8 A[4];
        #pragma unroll
        for (int kt = 0; kt < 4; ++kt) A[kt] = cat44(t[2*kt], t[2*kt+1]);
        #pragma unroll 2
        for (int nt = 0; nt < 8; ++nt){
            f32x4 acc = {0.f,0.f,0.f,0.f};
            #pragma unroll
            for (int kt = 0; kt < 4; ++kt)
                acc = MFMA16(A[kt], Wpk2[(nt*4+kt)*64 + lane], acc);
            int col = nt*16 + nl;
            float bb = b2[col];
            *(uint2*)&embb[col*16 + 4*kb] =
                make_uint2(pk2(fmaxf(acc[0]+bb,0.f), fmaxf(acc[1]+bb,0.f)),
                           pk2(fmaxf(acc[2]+bb,0.f), fmaxf(acc[3]+bb,0.f)));
        }
    }

    // ---- stage C: q,k,v = emb @ W{q,k,v} + b   [M=16,K=128,N=128] x3
    {
        unsigned ab = lds_lo(embb) + trofs;
        bf16x4 t[8];
        #pragma unroll
        for (int kt = 0; kt < 4; ++kt){
            t[2*kt]   = ds_tr(ab + kt*1024);
            t[2*kt+1] = ds_tr(ab + kt*1024 + 512);
        }
        lgkm0();
        bf16x8 A[4];
        #pragma unroll
        for (int kt = 0; kt < 4; ++kt) A[kt] = cat44(t[2*kt], t[2*kt+1]);
        #pragma unroll 2
        for (int nt = 0; nt < 8; ++nt){
            f32x4 aq={0.f,0.f,0.f,0.f}, ak={0.f,0.f,0.f,0.f}, av={0.f,0.f,0.f,0.f};
            #pragma unroll
            for (int kt = 0; kt < 4; ++kt){
                int fi = (nt*4+kt)*64 + lane;
                aq = MFMA16(A[kt], WpkQ[fi], aq);
                ak = MFMA16(A[kt], WpkK[fi], ak);
                av = MFMA16(A[kt], WpkV[fi], av);
            }
            int col = nt*16 + nl;
            float xq = bq[col], xk = bk_[col], xv = bv_[col];
            *(uint2*)&qbuf[col*16+4*kb] = make_uint2(pk2(aq[0]+xq,aq[1]+xq), pk2(aq[2]+xq,aq[3]+xq));
            *(uint2*)&kbuf[col*16+4*kb] = make_uint2(pk2(ak[0]+xk,ak[1]+xk), pk2(ak[2]+xk,ak[3]+xk));
            *(uint2*)&vbuf[col*16+4*kb] = make_uint2(pk2(av[0]+xv,av[1]+xv), pk2(av[2]+xv,av[3]+xv));
        }
    }

    // ---- stage D+E: attention per head (S^T = K@Q^T, softmax over regs, PV) + masked mean
    float mh[8];
    {
        const f32x4 zero = {0.f,0.f,0.f,0.f};
        unsigned qb_ = lds_lo(qbuf) + trofs;
        unsigned kb2 = lds_lo(kbuf) + trofs;
        bf16x4 qf[8], kf[8];
        #pragma unroll
        for (int h = 0; h < 8; ++h){
            qf[h] = ds_tr(qb_ + h*512);
            kf[h] = ds_tr(kb2 + h*512);
        }
        lgkm0();
        #pragma unroll
        for (int h = 0; h < 8; ++h){
            f32x4 st = MFMA16(cat40(kf[h]), cat40(qf[h]), zero); // rows j=4kb+r, col i=nl
            float sr[4];
            #pragma unroll
            for (int r = 0; r < 4; ++r)
                sr[r] = (4*kb+r < L) ? st[r]*0.25f : -3.0e38f;
            float mx = fmaxf(fmaxf(sr[0],sr[1]), fmaxf(sr[2],sr[3]));
            mx = fmaxf(mx, __shfl_xor(mx, 16));
            mx = fmaxf(mx, __shfl_xor(mx, 32));
            float pr[4], ps = 0.f;
            #pragma unroll
            for (int r = 0; r < 4; ++r){
                pr[r] = (4*kb+r < L) ? __expf(sr[r]-mx) : 0.f;
                ps += pr[r];
            }
            ps += __shfl_xor(ps, 16);
            ps += __shfl_xor(ps, 32);
            float inv = 1.f/ps;
            bf16x8 P;
            P[0]=f2bf(pr[0]*inv); P[1]=f2bf(pr[1]*inv);
            P[2]=f2bf(pr[2]*inv); P[3]=f2bf(pr[3]*inv);
            P[4]=0; P[5]=0; P[6]=0; P[7]=0;
            bf16x4 vf = *(const bf16x4*)&vbuf[(16*h+nl)*16 + 4*kb];
            f32x4 ctx = MFMA16(P, cat40(vf), zero);              // rows i=4kb+r, col d=nl
            float pm = 0.f;
            #pragma unroll
            for (int r = 0; r < 4; ++r) if (4*kb+r < L) pm += ctx[r];
            pm += __shfl_xor(pm, 16);
            pm += __shfl_xor(pm, 32);
            mh[h] = pm * invL;
        }
    }
    if (kb == 0){
        #pragma unroll
        for (int h = 0; h < 8; ++h)
            s_fused[(16*h + nl)*16 + w] = f2bf(mh[h]);   // mean parked in lane_ctx slot
    }
    __syncthreads();

    // ---- tail: load A-frags for Wo (mean) and Wp2 (ph1) before overwriting s_fused
    bf16x8 Am[4], Ap[4];
    {
        unsigned am = lds_lo(s_fused) + trofs;
        unsigned ap = lds_lo(s_ph1)   + trofs;
        bf16x4 t[16];
        #pragma unroll
        for (int kt = 0; kt < 4; ++kt){
            t[2*kt]     = ds_tr(am + kt*1024);
            t[2*kt+1]   = ds_tr(am + kt*1024 + 512);
            t[8+2*kt]   = ds_tr(ap + kt*1024);
            t[9+2*kt]   = ds_tr(ap + kt*1024 + 512);
        }
        lgkm0();
        #pragma unroll
        for (int kt = 0; kt < 4; ++kt){
            Am[kt] = cat44(t[2*kt],   t[2*kt+1]);
            Ap[kt] = cat44(t[8+2*kt], t[9+2*kt]);
        }
    }
    __syncthreads();
    {
        #pragma unroll
        for (int t2 = 0; t2 < 2; ++t2){
            int nt = 2*w + t2;
            f32x4 ao = {0.f,0.f,0.f,0.f}, ap2 = {0.f,0.f,0.f,0.f};
            #pragma unroll
            for (int kt = 0; kt < 4; ++kt){
                int fi = (nt*4+kt)*64 + lane;
                ao  = MFMA16(Am[kt], WpkO[fi],  ao);
                ap2 = MFMA16(Ap[kt], WpkP2[fi], ap2);
            }
            int col = nt*16 + nl;
            float xo = bo[col], xp = bp2[col];
            *(uint2*)&s_fused[col*16 + 4*kb] =
                make_uint2(pk2(ao[0]+xo, ao[1]+xo), pk2(ao[2]+xo, ao[3]+xo));
            *(uint2*)&s_fused[(128+col)*16 + 4*kb] =
                make_uint2(pk2(fmaxf(ap2[0]+xp,0.f), fmaxf(ap2[1]+xp,0.f)),
                           pk2(fmaxf(ap2[2]+xp,0.f), fmaxf(ap2[3]+xp,0.f)));
        }
    }
    __syncthreads();

    // ---- fusion layer 1: hf = relu(fused @ Wf1 + bf1)  [M=16,K=288,N=256]
    {
        unsigned ab = lds_lo(s_fused) + trofs;
        bf16x4 t[18];
        #pragma unroll
        for (int kt = 0; kt < 9; ++kt){
            t[2*kt]   = ds_tr(ab + kt*1024);
            t[2*kt+1] = ds_tr(ab + kt*1024 + 512);
        }
        lgkm0();
        bf16x8 A[9];
        #pragma unroll
        for (int kt = 0; kt < 9; ++kt) A[kt] = cat44(t[2*kt], t[2*kt+1]);
        #pragma unroll 2
        for (int t2 = 0; t2 < 4; ++t2){
            int nt = 4*w + t2;
            f32x4 acc = {0.f,0.f,0.f,0.f};
            #pragma unroll
            for (int kt = 0; kt < 9; ++kt)
                acc = MFMA16(A[kt], WpkF1[(nt*9+kt)*64 + lane], acc);
            int col = nt*16 + nl;
            float bb = bf1[col];
            *(uint2*)&hf[col*16 + 4*kb] =
                make_uint2(pk2(fmaxf(acc[0]+bb,0.f), fmaxf(acc[1]+bb,0.f)),
                           pk2(fmaxf(acc[2]+bb,0.f), fmaxf(acc[3]+bb,0.f)));
        }
    }
    __syncthreads();

    // ---- fusion layer 2: h = relu(hf @ Wf2 + bf2)  [M=16,K=256,N=256]
    {
        unsigned ab = lds_lo(hf) + trofs;
        bf16x4 t[16];
        #pragma unroll
        for (int kt = 0; kt < 8; ++kt){
            t[2*kt]   = ds_tr(ab + kt*1024);
            t[2*kt+1] = ds_tr(ab + kt*1024 + 512);
        }
        lgkm0();
        bf16x8 A[8];
        #pragma unroll
        for (int kt = 0; kt < 8; ++kt) A[kt] = cat44(t[2*kt], t[2*kt+1]);
        #pragma unroll 2
        for (int t2 = 0; t2 < 4; ++t2){
            int nt = 4*w + t2;
            f32x4 acc = {0.f,0.f,0.f,0.f};
            #pragma unroll
            for (int kt = 0; kt < 8; ++kt)
                acc = MFMA16(A[kt], WpkF2[(nt*8+kt)*64 + lane], acc);
            int col = nt*16 + nl;
            float bb = bf2_[col];
            *(uint2*)&hb[col*16 + 4*kb] =
                make_uint2(pk2(fmaxf(acc[0]+bb,0.f), fmaxf(acc[1]+bb,0.f)),
                           pk2(fmaxf(acc[2]+bb,0.f), fmaxf(acc[3]+bb,0.f)));
        }
    }
    __syncthreads();

    // ---- heads: wave w reduces row w (its TLS)
    {
        float sm = 0.f, sv = 0.f;
        #pragma unroll
        for (int i = 0; i < 4; ++i){
            int c = lane + 64*i;
            float hv = bf2f(hb[c*16 + w]);
            sm = fmaf(hv, Wm[c],   sm);
            sv = fmaf(hv, Wval[c], sv);
        }
        #pragma unroll
        for (int off = 32; off; off >>= 1){
            sm += __shfl_xor(sm, off);
            sv += __shfl_xor(sv, off);
        }
        if (lane == 0){
            out[n]          = sm + bm[0];
            out[NTLS + n]   = log_std[0];
            out[2*NTLS + n] = sv + bval[0];
        }
    }
}

extern "C" void kernel_launch(void* const* d_in, const int* in_sizes, int n_in,
                              void* d_out, int out_size, void* d_ws, size_t ws_size,
                              hipStream_t stream) {
    const float* queues       = (const float*)d_in[0];
    const float* waits        = (const float*)d_in[1];
    const float* phase_onehot = (const float*)d_in[2];
    const float* elapsed      = (const float*)d_in[3];
    const int*   lane_counts  = (const int*)d_in[4];
    const int*   region_ids   = (const int*)d_in[5];
    const float* W1  = (const float*)d_in[6];
    const float* b1  = (const float*)d_in[7];
    const float* W2  = (const float*)d_in[8];
    const float* b2  = (const float*)d_in[9];
    const float* Wq  = (const float*)d_in[10];
    const float* bq  = (const float*)d_in[11];
    const float* Wk  = (const float*)d_in[12];
    const float* bk  = (const float*)d_in[13];
    const float* Wv  = (const float*)d_in[14];
    const float* bv  = (const float*)d_in[15];
    const float* Wo  = (const float*)d_in[16];
    const float* bo  = (const float*)d_in[17];
    const float* Wp1 = (const float*)d_in[18];
    const float* bp1 = (const float*)d_in[19];
    const float* Wp2 = (const float*)d_in[20];
    const float* bp2 = (const float*)d_in[21];
    const float* region_table = (const float*)d_in[22];
    const float* Wf1 = (const float*)d_in[23];
    const float* bf1 = (const float*)d_in[24];
    const float* Wf2 = (const float*)d_in[25];
    const float* bf2 = (const float*)d_in[26];
    const float* Wm  = (const float*)d_in[27];
    const float* bm  = (const float*)d_in[28];
    const float* Wval = (const float*)d_in[29];
    const float* bval = (const float*)d_in[30];
    const float* log_std = (const float*)d_in[31];
    float* out = (float*)d_out;
    short* wpk = (short*)d_ws;   // 237568 bf16 = 475136 B of packed weights

    prepack<<<116, 256, 0, stream>>>(W2, Wq, Wk, Wv, Wo, Wp2, Wf1, Wf2, wpk);
    lane_ppo_mfma<<<4096, 256, 0, stream>>>(
        queues, waits, phase_onehot, elapsed, lane_counts, region_ids,
        W1, b1, b2, bq, bk, bv, bo, Wp1, bp1, bp2, region_table,
        bf1, bf2, Wm, bm, Wval, bval, log_std, wpk, out);
}

// Round 3
// 212.626 us; speedup vs baseline: 4.6970x; 1.3073x over previous
//
#include <hip/hip_runtime.h>
#include <hip/hip_bf16.h>
#include <stdint.h>

#define NTLS 16384

typedef float f32x4 __attribute__((ext_vector_type(4)));
typedef short bf16x8 __attribute__((ext_vector_type(8)));
typedef short bf16x4 __attribute__((ext_vector_type(4)));

__device__ __forceinline__ short f2bf(float x){
    union { float f; unsigned u; } v; v.f = x;
    unsigned r = (v.u + 0x7FFFu + ((v.u >> 16) & 1u)) >> 16;
    return (short)r;
}
__device__ __forceinline__ unsigned pk2(float a, float b){
    return ((unsigned)(unsigned short)f2bf(a)) | (((unsigned)(unsigned short)f2bf(b)) << 16);
}
__device__ __forceinline__ unsigned lds_lo(const void* p){
    return (unsigned)(size_t)p;
}
__device__ __forceinline__ bf16x4 ds_tr(unsigned addr){
    bf16x4 d;
    asm volatile("ds_read_b64_tr_b16 %0, %1" : "=v"(d) : "v"(addr) : "memory");
    return d;
}
__device__ __forceinline__ void lgkm0(){
    asm volatile("s_waitcnt lgkmcnt(0)" ::: "memory");
    __builtin_amdgcn_sched_barrier(0);
}
__device__ __forceinline__ bf16x8 cat44(bf16x4 lo, bf16x4 hi){
    bf16x8 r;
    r[0]=lo[0]; r[1]=lo[1]; r[2]=lo[2]; r[3]=lo[3];
    r[4]=hi[0]; r[5]=hi[1]; r[6]=hi[2]; r[7]=hi[3];
    return r;
}
__device__ __forceinline__ bf16x8 cat40(bf16x4 lo){
    bf16x8 r;
    r[0]=lo[0]; r[1]=lo[1]; r[2]=lo[2]; r[3]=lo[3];
    r[4]=0; r[5]=0; r[6]=0; r[7]=0;
    return r;
}
#define MFMA16(a,b,c) __builtin_amdgcn_mfma_f32_16x16x32_bf16((a),(b),(c),0,0,0)

// ---------------- weight prepack (unchanged, verified): fp32 row-major -> bf16 frag-linear
__global__ __launch_bounds__(256) void prepack(
    const float* __restrict__ W2, const float* __restrict__ Wq,
    const float* __restrict__ Wk, const float* __restrict__ Wv,
    const float* __restrict__ Wo, const float* __restrict__ Wp2,
    const float* __restrict__ Wf1, const float* __restrict__ Wf2,
    short* __restrict__ out)
{
    int gid = blockIdx.x * 256 + threadIdx.x;      // 0..29695
    const float* src; short* dst; int K, Nn; int id = gid;
    if (id < 12288){
        int wsel = id >> 11; id &= 2047;
        const float* tab[6] = {W2, Wq, Wk, Wv, Wo, Wp2};
        src = tab[wsel]; dst = out + wsel * 16384; K = 128; Nn = 128;
    } else if (id < 21504){
        id -= 12288; src = Wf1; dst = out + 98304; K = 288; Nn = 256;
    } else {
        id -= 21504; src = Wf2; dst = out + 172032; K = 256; Nn = 256;
    }
    int lane = id & 63, f = id >> 6;
    int KT = K >> 5;
    int nt = f / KT, kt = f - nt * KT;
    int n  = nt * 16 + (lane & 15);
    int kb = kt * 32 + 4 * (lane >> 4);
    unsigned w0 = pk2(src[(kb+0)*Nn+n],  src[(kb+1)*Nn+n]);
    unsigned w1 = pk2(src[(kb+2)*Nn+n],  src[(kb+3)*Nn+n]);
    unsigned w2 = pk2(src[(kb+16)*Nn+n], src[(kb+17)*Nn+n]);
    unsigned w3 = pk2(src[(kb+18)*Nn+n], src[(kb+19)*Nn+n]);
    *(uint4*)&dst[(f*64+lane)*8] = make_uint4(w0,w1,w2,w3);
}

// ============ kernel 1: lane pipeline, 8 TLS/block, waves split N ============
__global__ __launch_bounds__(256, 2) void k1_lane(
    const float* __restrict__ queues, const float* __restrict__ waits,
    const float* __restrict__ elapsed, const int* __restrict__ lane_counts,
    const float* __restrict__ W1, const float* __restrict__ b1,
    const float* __restrict__ b2,
    const float* __restrict__ bq, const float* __restrict__ bk_, const float* __restrict__ bv_,
    const short* __restrict__ wpk,
    short* __restrict__ meanb)
{
    const int tid  = threadIdx.x;
    const int w    = tid >> 6, lane = tid & 63;
    const int nl   = lane & 15, kb = lane >> 4;
    const int base = blockIdx.x << 3;

    __shared__ __align__(512) short s_h1[8*2048];  // h1; later: 4 wave-private qkv dbufs
    __shared__ __align__(512) short s_emb[8*2048]; // emb

    const unsigned trofs = (unsigned)(kb*128 + nl*8);
    const bf16x8* Wpk2 = (const bf16x8*)(wpk);
    const bf16x8* WpkQ = (const bf16x8*)(wpk + 16384);
    const bf16x8* WpkK = (const bf16x8*)(wpk + 32768);
    const bf16x8* WpkV = (const bf16x8*)(wpk + 49152);

    // ---- stage A: h1 = relu(lane_feats @ W1 + b1), wave w handles TLS {w, w+4}
    #pragma unroll
    for (int tt = 0; tt < 2; ++tt){
        const int t = w + 4*tt, n = base + t;
        const float ev = elapsed[n];
        float qv = queues[n*16 + nl];
        float wv = waits [n*16 + nl];
        float qm[4], wmv[4];
        #pragma unroll
        for (int r = 0; r < 4; ++r){
            qm[r]  = __shfl(qv, 4*kb + r, 16);
            wmv[r] = __shfl(wv, 4*kb + r, 16);
        }
        #pragma unroll
        for (int i = 0; i < 8; ++i){
            int c = nl + 16*i;
            float w0 = W1[c], w1 = W1[128+c], w2 = W1[256+c], bb = b1[c];
            float v0 = fmaxf(fmaf(qm[0], w0, fmaf(wmv[0], w1, fmaf(ev, w2, bb))), 0.f);
            float v1 = fmaxf(fmaf(qm[1], w0, fmaf(wmv[1], w1, fmaf(ev, w2, bb))), 0.f);
            float v2 = fmaxf(fmaf(qm[2], w0, fmaf(wmv[2], w1, fmaf(ev, w2, bb))), 0.f);
            float v3 = fmaxf(fmaf(qm[3], w0, fmaf(wmv[3], w1, fmaf(ev, w2, bb))), 0.f);
            *(uint2*)&s_h1[t*2048 + c*16 + 4*kb] = make_uint2(pk2(v0,v1), pk2(v2,v3));
        }
    }
    __syncthreads();

    // ---- stage B: emb = relu(h1 @ W2 + b2); wave w owns cols [32w,32w+32), loops 8 TLS
    {
        bf16x8 B[8];
        #pragma unroll
        for (int nt2 = 0; nt2 < 2; ++nt2)
            #pragma unroll
            for (int kt = 0; kt < 4; ++kt)
                B[nt2*4+kt] = Wpk2[((2*w+nt2)*4+kt)*64 + lane];
        const int c0 = 32*w + nl, c1 = c0 + 16;
        const float bb0 = b2[c0], bb1 = b2[c1];
        for (int t = 0; t < 8; ++t){
            unsigned ab = lds_lo(s_h1) + t*4096 + trofs;
            bf16x4 tr[8];
            #pragma unroll
            for (int kt = 0; kt < 4; ++kt){
                tr[2*kt]   = ds_tr(ab + kt*1024);
                tr[2*kt+1] = ds_tr(ab + kt*1024 + 512);
            }
            lgkm0();
            bf16x8 A[4];
            #pragma unroll
            for (int kt = 0; kt < 4; ++kt) A[kt] = cat44(tr[2*kt], tr[2*kt+1]);
            f32x4 a0 = {0.f,0.f,0.f,0.f}, a1 = {0.f,0.f,0.f,0.f};
            #pragma unroll
            for (int kt = 0; kt < 4; ++kt){
                a0 = MFMA16(A[kt], B[kt],   a0);
                a1 = MFMA16(A[kt], B[4+kt], a1);
            }
            *(uint2*)&s_emb[t*2048 + c0*16 + 4*kb] =
                make_uint2(pk2(fmaxf(a0[0]+bb0,0.f), fmaxf(a0[1]+bb0,0.f)),
                           pk2(fmaxf(a0[2]+bb0,0.f), fmaxf(a0[3]+bb0,0.f)));
            *(uint2*)&s_emb[t*2048 + c1*16 + 4*kb] =
                make_uint2(pk2(fmaxf(a1[0]+bb1,0.f), fmaxf(a1[1]+bb1,0.f)),
                           pk2(fmaxf(a1[2]+bb1,0.f), fmaxf(a1[3]+bb1,0.f)));
        }
    }
    __syncthreads();

    // ---- stage C + attention: wave w owns heads {2w, 2w+1}; wave-private qkv dbuf in s_h1
    {
        bf16x8 BQ[8], BK[8], BV[8];
        #pragma unroll
        for (int nt2 = 0; nt2 < 2; ++nt2)
            #pragma unroll
            for (int kt = 0; kt < 4; ++kt){
                int fi = ((2*w+nt2)*4+kt)*64 + lane;
                BQ[nt2*4+kt] = WpkQ[fi];
                BK[nt2*4+kt] = WpkK[fi];
                BV[nt2*4+kt] = WpkV[fi];
            }
        const int c0 = 32*w + nl, c1 = c0 + 16;
        const float xq0 = bq[c0],  xq1 = bq[c1];
        const float xk0 = bk_[c0], xk1 = bk_[c1];
        const float xv0 = bv_[c0], xv1 = bv_[c1];
        short* wavebuf = s_h1 + w*4096;        // 8192 B per wave (2 bufs x 4096 B)
        const f32x4 zero = {0.f,0.f,0.f,0.f};

        for (int t = 0; t < 8; ++t){
            const int n = base + t;
            const int L = lane_counts[n];
            const float invL = 1.f / (float)L;

            unsigned ab = lds_lo(s_emb) + t*4096 + trofs;
            bf16x4 tr[8];
            #pragma unroll
            for (int kt = 0; kt < 4; ++kt){
                tr[2*kt]   = ds_tr(ab + kt*1024);
                tr[2*kt+1] = ds_tr(ab + kt*1024 + 512);
            }
            lgkm0();
            bf16x8 A[4];
            #pragma unroll
            for (int kt = 0; kt < 4; ++kt) A[kt] = cat44(tr[2*kt], tr[2*kt+1]);

            f32x4 q0=zero,q1=zero,k0=zero,k1=zero,v0=zero,v1=zero;
            #pragma unroll
            for (int kt = 0; kt < 4; ++kt){
                q0 = MFMA16(A[kt], BQ[kt],   q0);
                k0 = MFMA16(A[kt], BK[kt],   k0);
                v0 = MFMA16(A[kt], BV[kt],   v0);
                q1 = MFMA16(A[kt], BQ[4+kt], q1);
                k1 = MFMA16(A[kt], BK[4+kt], k1);
                v1 = MFMA16(A[kt], BV[4+kt], v1);
            }
            short* buf = wavebuf + (t&1)*2048;   // q[0,512) k[512,1024) v[1024,1536) shorts
            *(uint2*)&buf[nl*16 + 4*kb] =
                make_uint2(pk2(q0[0]+xq0,q0[1]+xq0), pk2(q0[2]+xq0,q0[3]+xq0));
            *(uint2*)&buf[(16+nl)*16 + 4*kb] =
                make_uint2(pk2(q1[0]+xq1,q1[1]+xq1), pk2(q1[2]+xq1,q1[3]+xq1));
            *(uint2*)&buf[512 + nl*16 + 4*kb] =
                make_uint2(pk2(k0[0]+xk0,k0[1]+xk0), pk2(k0[2]+xk0,k0[3]+xk0));
            *(uint2*)&buf[512 + (16+nl)*16 + 4*kb] =
                make_uint2(pk2(k1[0]+xk1,k1[1]+xk1), pk2(k1[2]+xk1,k1[3]+xk1));
            *(uint2*)&buf[1024 + nl*16 + 4*kb] =
                make_uint2(pk2(v0[0]+xv0,v0[1]+xv0), pk2(v0[2]+xv0,v0[3]+xv0));
            *(uint2*)&buf[1024 + (16+nl)*16 + 4*kb] =
                make_uint2(pk2(v1[0]+xv1,v1[1]+xv1), pk2(v1[2]+xv1,v1[3]+xv1));
            lgkm0();

            const unsigned bb = lds_lo(buf);
            #pragma unroll
            for (int hl = 0; hl < 2; ++hl){
                bf16x4 qf = ds_tr(bb + trofs + hl*512);
                bf16x4 kf = ds_tr(bb + 1024 + trofs + hl*512);
                lgkm0();
                f32x4 st = MFMA16(cat40(kf), cat40(qf), zero); // rows j=4kb+r, col i=nl
                float sr[4];
                #pragma unroll
                for (int r = 0; r < 4; ++r)
                    sr[r] = (4*kb+r < L) ? st[r]*0.25f : -3.0e38f;
                float mx = fmaxf(fmaxf(sr[0],sr[1]), fmaxf(sr[2],sr[3]));
                mx = fmaxf(mx, __shfl_xor(mx, 16));
                mx = fmaxf(mx, __shfl_xor(mx, 32));
                float pr[4], ps = 0.f;
                #pragma unroll
                for (int r = 0; r < 4; ++r){
                    pr[r] = (4*kb+r < L) ? __expf(sr[r]-mx) : 0.f;
                    ps += pr[r];
                }
                ps += __shfl_xor(ps, 16);
                ps += __shfl_xor(ps, 32);
                float inv = 1.f/ps;
                bf16x8 P;
                P[0]=f2bf(pr[0]*inv); P[1]=f2bf(pr[1]*inv);
                P[2]=f2bf(pr[2]*inv); P[3]=f2bf(pr[3]*inv);
                P[4]=0; P[5]=0; P[6]=0; P[7]=0;
                bf16x4 vf = *(const bf16x4*)&buf[1024 + (hl*16+nl)*16 + 4*kb];
                f32x4 ctx = MFMA16(P, cat40(vf), zero);        // rows i=4kb+r, col d=nl
                float pm = 0.f;
                #pragma unroll
                for (int r = 0; r < 4; ++r) if (4*kb+r < L) pm += ctx[r];
                pm += __shfl_xor(pm, 16);
                pm += __shfl_xor(pm, 32);
                if (kb == 0)
                    meanb[(n>>4)*2048 + (32*w + hl*16 + nl)*16 + (n&15)] = f2bf(pm * invL);
            }
        }
    }
}

// ============ kernel 2: tail (Wo/phase/region -> F1 -> F2 -> heads), 32 TLS/block ============
__global__ __launch_bounds__(256, 2) void k2_tail(
    const float* __restrict__ phase_onehot, const float* __restrict__ elapsed,
    const int* __restrict__ region_ids, const float* __restrict__ region_table,
    const float* __restrict__ Wp1, const float* __restrict__ bp1, const float* __restrict__ bp2,
    const float* __restrict__ bo,
    const float* __restrict__ bf1, const float* __restrict__ bf2_,
    const float* __restrict__ Wm, const float* __restrict__ bm,
    const float* __restrict__ Wval, const float* __restrict__ bval,
    const float* __restrict__ log_std,
    const short* __restrict__ wpk, const short* __restrict__ meanb,
    float* __restrict__ out)
{
    const int tid  = threadIdx.x;
    const int w    = tid >> 6, lane = tid & 63;
    const int nl   = lane & 15, kb = lane >> 4;
    const int base = blockIdx.x << 5;   // 32 TLS

    __shared__ __align__(512) short s_mean[2*2048];   // 8 KB
    __shared__ __align__(512) short s_ph1[2*2048];    // 8 KB
    __shared__ __align__(512) short s_fused[2*4608];  // 18 KB
    __shared__ __align__(512) short s_hf[2*4096];     // 16 KB
    __shared__ float s_part[4][2][16][2];             // 1 KB

    const unsigned trofs = (unsigned)(kb*128 + nl*8);
    const bf16x8* WpkO  = (const bf16x8*)(wpk + 65536);
    const bf16x8* WpkP2 = (const bf16x8*)(wpk + 81920);
    const bf16x8* WpkF1 = (const bf16x8*)(wpk + 98304);
    const bf16x8* WpkF2 = (const bf16x8*)(wpk + 172032);

    // 1. copy mean chunk (already col-major-16 in global) -> LDS, linear
    {
        const uint4* src = (const uint4*)(meanb + base*128);
        uint4* dst = (uint4*)s_mean;
        dst[tid]       = src[tid];
        dst[256 + tid] = src[256 + tid];
    }
    // 2. phase hidden: thread -> TLS r = tid>>3, cols 16*(tid&7)..+16
    {
        const int r = tid >> 3, cb = tid & 7, n = base + r;
        const float p0 = phase_onehot[n*4+0], p1 = phase_onehot[n*4+1];
        const float p2 = phase_onehot[n*4+2], p3 = phase_onehot[n*4+3];
        const float ev = elapsed[n];
        #pragma unroll
        for (int jc = 0; jc < 16; ++jc){
            int c = cb*16 + jc;
            float a = fmaf(p0, Wp1[c], fmaf(p1, Wp1[128+c], fmaf(p2, Wp1[256+c],
                      fmaf(p3, Wp1[384+c], fmaf(ev, Wp1[512+c], bp1[c])))));
            s_ph1[(r>>4)*2048 + c*16 + (r&15)] = f2bf(fmaxf(a, 0.f));
        }
        // 3. region embedding -> fused cols [256,288)
        const int rid = region_ids[n];
        #pragma unroll
        for (int jc = 0; jc < 4; ++jc){
            int c = (tid&7)*4 + jc;
            s_fused[(r>>4)*4608 + (256+c)*16 + (r&15)] = f2bf(region_table[rid*32 + c]);
        }
    }
    __syncthreads();

    // 4. Wo (no relu) + Wp2 (relu): wave w owns nt {2w,2w+1}
    {
        bf16x8 BO[8], BP[8];
        #pragma unroll
        for (int nt2 = 0; nt2 < 2; ++nt2)
            #pragma unroll
            for (int kt = 0; kt < 4; ++kt){
                int fi = ((2*w+nt2)*4+kt)*64 + lane;
                BO[nt2*4+kt] = WpkO[fi];
                BP[nt2*4+kt] = WpkP2[fi];
            }
        const int c0 = 32*w + nl, c1 = c0 + 16;
        const float o0b = bo[c0], o1b = bo[c1];
        const float p0b = bp2[c0], p1b = bp2[c1];
        #pragma unroll
        for (int mt = 0; mt < 2; ++mt){
            unsigned am = lds_lo(s_mean) + mt*4096 + trofs;
            unsigned ap = lds_lo(s_ph1)  + mt*4096 + trofs;
            bf16x4 t[16];
            #pragma unroll
            for (int kt = 0; kt < 4; ++kt){
                t[2*kt]     = ds_tr(am + kt*1024);
                t[2*kt+1]   = ds_tr(am + kt*1024 + 512);
                t[8+2*kt]   = ds_tr(ap + kt*1024);
                t[9+2*kt]   = ds_tr(ap + kt*1024 + 512);
            }
            lgkm0();
            f32x4 o0={0.f,0.f,0.f,0.f}, o1=o0, p0=o0, p1=o0;
            #pragma unroll
            for (int kt = 0; kt < 4; ++kt){
                bf16x8 Am = cat44(t[2*kt],   t[2*kt+1]);
                bf16x8 Ap = cat44(t[8+2*kt], t[9+2*kt]);
                o0 = MFMA16(Am, BO[kt],   o0);
                o1 = MFMA16(Am, BO[4+kt], o1);
                p0 = MFMA16(Ap, BP[kt],   p0);
                p1 = MFMA16(Ap, BP[4+kt], p1);
            }
            short* fb = s_fused + mt*4608;
            *(uint2*)&fb[c0*16 + 4*kb] =
                make_uint2(pk2(o0[0]+o0b, o0[1]+o0b), pk2(o0[2]+o0b, o0[3]+o0b));
            *(uint2*)&fb[c1*16 + 4*kb] =
                make_uint2(pk2(o1[0]+o1b, o1[1]+o1b), pk2(o1[2]+o1b, o1[3]+o1b));
            *(uint2*)&fb[(128+c0)*16 + 4*kb] =
                make_uint2(pk2(fmaxf(p0[0]+p0b,0.f), fmaxf(p0[1]+p0b,0.f)),
                           pk2(fmaxf(p0[2]+p0b,0.f), fmaxf(p0[3]+p0b,0.f)));
            *(uint2*)&fb[(128+c1)*16 + 4*kb] =
                make_uint2(pk2(fmaxf(p1[0]+p1b,0.f), fmaxf(p1[1]+p1b,0.f)),
                           pk2(fmaxf(p1[2]+p1b,0.f), fmaxf(p1[3]+p1b,0.f)));
        }
    }
    __syncthreads();

    // 5. F1: hf = relu(fused @ Wf1 + bf1), K=288; wave w owns nt {4w..4w+3}
    {
        bf16x8 A[2][9];
        #pragma unroll
        for (int mt = 0; mt < 2; ++mt){
            unsigned ab = lds_lo(s_fused) + mt*9216 + trofs;
            bf16x4 t[18];
            #pragma unroll
            for (int kt = 0; kt < 9; ++kt){
                t[2*kt]   = ds_tr(ab + kt*1024);
                t[2*kt+1] = ds_tr(ab + kt*1024 + 512);
            }
            lgkm0();
            #pragma unroll
            for (int kt = 0; kt < 9; ++kt) A[mt][kt] = cat44(t[2*kt], t[2*kt+1]);
        }
        #pragma unroll
        for (int nt2 = 0; nt2 < 4; ++nt2){
            const int nt = 4*w + nt2;
            bf16x8 Bf[9];
            #pragma unroll
            for (int kt = 0; kt < 9; ++kt) Bf[kt] = WpkF1[(nt*9+kt)*64 + lane];
            f32x4 a0 = {0.f,0.f,0.f,0.f}, a1 = a0;
            #pragma unroll
            for (int kt = 0; kt < 9; ++kt){
                a0 = MFMA16(A[0][kt], Bf[kt], a0);
                a1 = MFMA16(A[1][kt], Bf[kt], a1);
            }
            const int c = nt*16 + nl;
            const float bb = bf1[c];
            *(uint2*)&s_hf[c*16 + 4*kb] =
                make_uint2(pk2(fmaxf(a0[0]+bb,0.f), fmaxf(a0[1]+bb,0.f)),
                           pk2(fmaxf(a0[2]+bb,0.f), fmaxf(a0[3]+bb,0.f)));
            *(uint2*)&s_hf[4096 + c*16 + 4*kb] =
                make_uint2(pk2(fmaxf(a1[0]+bb,0.f), fmaxf(a1[1]+bb,0.f)),
                           pk2(fmaxf(a1[2]+bb,0.f), fmaxf(a1[3]+bb,0.f)));
        }
    }
    __syncthreads();

    // 6. F2 + heads epilogue (no hb buffer): wave w owns nt {4w..4w+3}
    {
        bf16x8 A[2][8];
        #pragma unroll
        for (int mt = 0; mt < 2; ++mt){
            unsigned ab = lds_lo(s_hf) + mt*8192 + trofs;
            bf16x4 t[16];
            #pragma unroll
            for (int kt = 0; kt < 8; ++kt){
                t[2*kt]   = ds_tr(ab + kt*1024);
                t[2*kt+1] = ds_tr(ab + kt*1024 + 512);
            }
            lgkm0();
            #pragma unroll
            for (int kt = 0; kt < 8; ++kt) A[mt][kt] = cat44(t[2*kt], t[2*kt+1]);
        }
        float sm0[4] = {0,0,0,0}, sv0[4] = {0,0,0,0};
        float sm1[4] = {0,0,0,0}, sv1[4] = {0,0,0,0};
        #pragma unroll
        for (int nt2 = 0; nt2 < 4; ++nt2){
            const int nt = 4*w + nt2;
            bf16x8 Bf[8];
            #pragma unroll
            for (int kt = 0; kt < 8; ++kt) Bf[kt] = WpkF2[(nt*8+kt)*64 + lane];
            f32x4 a0 = {0.f,0.f,0.f,0.f}, a1 = a0;
            #pragma unroll
            for (int kt = 0; kt < 8; ++kt){
                a0 = MFMA16(A[0][kt], Bf[kt], a0);
                a1 = MFMA16(A[1][kt], Bf[kt], a1);
            }
            const int c = nt*16 + nl;
            const float bb = bf2_[c], wm = Wm[c], wv = Wval[c];
            #pragma unroll
            for (int r = 0; r < 4; ++r){
                float h0 = fmaxf(a0[r]+bb, 0.f);
                float h1 = fmaxf(a1[r]+bb, 0.f);
                sm0[r] = fmaf(h0, wm, sm0[r]);  sv0[r] = fmaf(h0, wv, sv0[r]);
                sm1[r] = fmaf(h1, wm, sm1[r]);  sv1[r] = fmaf(h1, wv, sv1[r]);
            }
        }
        #pragma unroll
        for (int off = 1; off < 16; off <<= 1){
            #pragma unroll
            for (int r = 0; r < 4; ++r){
                sm0[r] += __shfl_xor(sm0[r], off);  sv0[r] += __shfl_xor(sv0[r], off);
                sm1[r] += __shfl_xor(sm1[r], off);  sv1[r] += __shfl_xor(sv1[r], off);
            }
        }
        if (nl == 0){
            #pragma unroll
            for (int r = 0; r < 4; ++r){
                s_part[w][0][4*kb+r][0] = sm0[r];  s_part[w][0][4*kb+r][1] = sv0[r];
                s_part[w][1][4*kb+r][0] = sm1[r];  s_part[w][1][4*kb+r][1] = sv1[r];
            }
        }
    }
    __syncthreads();

    // 7. finalize
    if (tid < 32){
        const int r = tid, n = base + r;
        float sm = bm[0], sv = bval[0];
        #pragma unroll
        for (int ww = 0; ww < 4; ++ww){
            sm += s_part[ww][r>>4][r&15][0];
            sv += s_part[ww][r>>4][r&15][1];
        }
        out[n]          = sm;
        out[NTLS + n]   = log_std[0];
        out[2*NTLS + n] = sv;
    }
}

extern "C" void kernel_launch(void* const* d_in, const int* in_sizes, int n_in,
                              void* d_out, int out_size, void* d_ws, size_t ws_size,
                              hipStream_t stream) {
    const float* queues       = (const float*)d_in[0];
    const float* waits        = (const float*)d_in[1];
    const float* phase_onehot = (const float*)d_in[2];
    const float* elapsed      = (const float*)d_in[3];
    const int*   lane_counts  = (const int*)d_in[4];
    const int*   region_ids   = (const int*)d_in[5];
    const float* W1  = (const float*)d_in[6];
    const float* b1  = (const float*)d_in[7];
    const float* W2  = (const float*)d_in[8];
    const float* b2  = (const float*)d_in[9];
    const float* Wq  = (const float*)d_in[10];
    const float* bq  = (const float*)d_in[11];
    const float* Wk  = (const float*)d_in[12];
    const float* bk  = (const float*)d_in[13];
    const float* Wv  = (const float*)d_in[14];
    const float* bv  = (const float*)d_in[15];
    const float* Wo  = (const float*)d_in[16];
    const float* bo  = (const float*)d_in[17];
    const float* Wp1 = (const float*)d_in[18];
    const float* bp1 = (const float*)d_in[19];
    const float* Wp2 = (const float*)d_in[20];
    const float* bp2 = (const float*)d_in[21];
    const float* region_table = (const float*)d_in[22];
    const float* Wf1 = (const float*)d_in[23];
    const float* bf1 = (const float*)d_in[24];
    const float* Wf2 = (const float*)d_in[25];
    const float* bf2 = (const float*)d_in[26];
    const float* Wm  = (const float*)d_in[27];
    const float* bm  = (const float*)d_in[28];
    const float* Wval = (const float*)d_in[29];
    const float* bval = (const float*)d_in[30];
    const float* log_std = (const float*)d_in[31];
    float* out = (float*)d_out;

    short* wpk   = (short*)d_ws;                          // 475136 B packed weights
    short* meanb = (short*)((char*)d_ws + 524288);        // 4 MB col-major-16 mean

    prepack<<<116, 256, 0, stream>>>(W2, Wq, Wk, Wv, Wo, Wp2, Wf1, Wf2, wpk);
    k1_lane<<<2048, 256, 0, stream>>>(
        queues, waits, elapsed, lane_counts,
        W1, b1, b2, bq, bk, bv, wpk, meanb);
    k2_tail<<<512, 256, 0, stream>>>(
        phase_onehot, elapsed, region_ids, region_table,
        Wp1, bp1, bp2, bo, bf1, bf2, Wm, bm, Wval, bval, log_std,
        wpk, meanb, out);
}

// Round 4
// 190.219 us; speedup vs baseline: 5.2503x; 1.1178x over previous
//
#include <hip/hip_runtime.h>
#include <hip/hip_bf16.h>
#include <stdint.h>

#define NTLS 16384

typedef float f32x4 __attribute__((ext_vector_type(4)));
typedef short bf16x8 __attribute__((ext_vector_type(8)));
typedef short bf16x4 __attribute__((ext_vector_type(4)));

// packed fp32->bf16 (RNE) via native instruction: 1 VALU op for 2 values
__device__ __forceinline__ unsigned pk2(float a, float b){
    unsigned r;
    asm("v_cvt_pk_bf16_f32 %0, %1, %2" : "=v"(r) : "v"(a), "v"(b));
    return r;
}
__device__ __forceinline__ short f2bf(float x){
    return (short)(pk2(x, 0.f) & 0xffff);
}
__device__ __forceinline__ unsigned lds_lo(const void* p){
    return (unsigned)(size_t)p;
}
__device__ __forceinline__ bf16x4 ds_tr(unsigned addr){
    bf16x4 d;
    asm volatile("ds_read_b64_tr_b16 %0, %1" : "=v"(d) : "v"(addr) : "memory");
    return d;
}
__device__ __forceinline__ void lgkm0(){
    asm volatile("s_waitcnt lgkmcnt(0)" ::: "memory");
    __builtin_amdgcn_sched_barrier(0);
}
__device__ __forceinline__ bf16x8 cat44(bf16x4 lo, bf16x4 hi){
    bf16x8 r;
    r[0]=lo[0]; r[1]=lo[1]; r[2]=lo[2]; r[3]=lo[3];
    r[4]=hi[0]; r[5]=hi[1]; r[6]=hi[2]; r[7]=hi[3];
    return r;
}
__device__ __forceinline__ bf16x8 cat40(bf16x4 lo){
    bf16x8 r;
    r[0]=lo[0]; r[1]=lo[1]; r[2]=lo[2]; r[3]=lo[3];
    r[4]=0; r[5]=0; r[6]=0; r[7]=0;
    return r;
}
#define MFMA16(a,b,c) __builtin_amdgcn_mfma_f32_16x16x32_bf16((a),(b),(c),0,0,0)

// ---------------- weight prepack (verified): fp32 row-major -> bf16 frag-linear
__global__ __launch_bounds__(256) void prepack(
    const float* __restrict__ W2, const float* __restrict__ Wq,
    const float* __restrict__ Wk, const float* __restrict__ Wv,
    const float* __restrict__ Wo, const float* __restrict__ Wp2,
    const float* __restrict__ Wf1, const float* __restrict__ Wf2,
    short* __restrict__ out)
{
    int gid = blockIdx.x * 256 + threadIdx.x;      // 0..29695
    const float* src; short* dst; int K, Nn; int id = gid;
    if (id < 12288){
        int wsel = id >> 11; id &= 2047;
        const float* tab[6] = {W2, Wq, Wk, Wv, Wo, Wp2};
        src = tab[wsel]; dst = out + wsel * 16384; K = 128; Nn = 128;
    } else if (id < 21504){
        id -= 12288; src = Wf1; dst = out + 98304; K = 288; Nn = 256;
    } else {
        id -= 21504; src = Wf2; dst = out + 172032; K = 256; Nn = 256;
    }
    int lane = id & 63, f = id >> 6;
    int KT = K >> 5;
    int nt = f / KT, kt = f - nt * KT;
    int n  = nt * 16 + (lane & 15);
    int kb = kt * 32 + 4 * (lane >> 4);
    unsigned w0 = pk2(src[(kb+0)*Nn+n],  src[(kb+1)*Nn+n]);
    unsigned w1 = pk2(src[(kb+2)*Nn+n],  src[(kb+3)*Nn+n]);
    unsigned w2 = pk2(src[(kb+16)*Nn+n], src[(kb+17)*Nn+n]);
    unsigned w3 = pk2(src[(kb+18)*Nn+n], src[(kb+19)*Nn+n]);
    *(uint4*)&dst[(f*64+lane)*8] = make_uint4(w0,w1,w2,w3);
}

// ============ kernel 1: lane pipeline, 8 TLS/block, 8 waves, head-per-wave ============
__global__ __launch_bounds__(512, 4) void k1_lane(
    const float* __restrict__ queues, const float* __restrict__ waits,
    const float* __restrict__ elapsed, const int* __restrict__ lane_counts,
    const float* __restrict__ W1, const float* __restrict__ b1,
    const float* __restrict__ b2,
    const float* __restrict__ bq, const float* __restrict__ bk_, const float* __restrict__ bv_,
    const short* __restrict__ wpk,
    short* __restrict__ meanb)
{
    const int tid  = threadIdx.x;
    const int w    = tid >> 6, lane = tid & 63;
    const int nl   = lane & 15, kb = lane >> 4;
    const int base = blockIdx.x << 3;

    __shared__ __align__(512) short s_h1[8*2048];   // 32KB; stage C: wave-private qkv bufs
    __shared__ __align__(512) short s_emb[8*2048];  // 32KB

    const unsigned trofs = (unsigned)(kb*128 + nl*8);
    const bf16x8* Wpk2 = (const bf16x8*)(wpk);
    const bf16x8* WpkQ = (const bf16x8*)(wpk + 16384);
    const bf16x8* WpkK = (const bf16x8*)(wpk + 32768);
    const bf16x8* WpkV = (const bf16x8*)(wpk + 49152);

    // ---- stage A: wave w computes h1 for TLS w (all 128 cols, 16 rows)
    {
        const int n = base + w;
        const float ev = elapsed[n];
        float qv = queues[n*16 + nl];
        float wv = waits [n*16 + nl];
        float qm[4], wmv[4];
        #pragma unroll
        for (int r = 0; r < 4; ++r){
            qm[r]  = __shfl(qv, 4*kb + r, 16);
            wmv[r] = __shfl(wv, 4*kb + r, 16);
        }
        #pragma unroll
        for (int i = 0; i < 8; ++i){
            int c = nl + 16*i;
            float w0 = W1[c], w1 = W1[128+c], w2 = W1[256+c], bb = b1[c];
            float v0 = fmaxf(fmaf(qm[0], w0, fmaf(wmv[0], w1, fmaf(ev, w2, bb))), 0.f);
            float v1 = fmaxf(fmaf(qm[1], w0, fmaf(wmv[1], w1, fmaf(ev, w2, bb))), 0.f);
            float v2 = fmaxf(fmaf(qm[2], w0, fmaf(wmv[2], w1, fmaf(ev, w2, bb))), 0.f);
            float v3 = fmaxf(fmaf(qm[3], w0, fmaf(wmv[3], w1, fmaf(ev, w2, bb))), 0.f);
            *(uint2*)&s_h1[w*2048 + c*16 + 4*kb] = make_uint2(pk2(v0,v1), pk2(v2,v3));
        }
    }
    __syncthreads();

    // ---- stage B: emb = relu(h1 @ W2 + b2); wave w owns cols [16w,16w+16), loops 8 TLS
    {
        bf16x8 B2[4];
        #pragma unroll
        for (int kt = 0; kt < 4; ++kt) B2[kt] = Wpk2[(w*4+kt)*64 + lane];
        const int c0 = 16*w + nl;
        const float bb0 = b2[c0];
        for (int t = 0; t < 8; ++t){
            unsigned ab = lds_lo(s_h1) + t*4096 + trofs;
            bf16x4 tr[8];
            #pragma unroll
            for (int kt = 0; kt < 4; ++kt){
                tr[2*kt]   = ds_tr(ab + kt*1024);
                tr[2*kt+1] = ds_tr(ab + kt*1024 + 512);
            }
            lgkm0();
            f32x4 a0 = {0.f,0.f,0.f,0.f};
            #pragma unroll
            for (int kt = 0; kt < 4; ++kt)
                a0 = MFMA16(cat44(tr[2*kt], tr[2*kt+1]), B2[kt], a0);
            *(uint2*)&s_emb[t*2048 + c0*16 + 4*kb] =
                make_uint2(pk2(fmaxf(a0[0]+bb0,0.f), fmaxf(a0[1]+bb0,0.f)),
                           pk2(fmaxf(a0[2]+bb0,0.f), fmaxf(a0[3]+bb0,0.f)));
        }
    }
    __syncthreads();   // also: all stage-B reads of s_h1 done -> safe to overlay qkv bufs

    // ---- stage C + attention: wave w owns head w (cols [16w,16w+16))
    {
        bf16x8 BQ[4], BK[4], BV[4];
        #pragma unroll
        for (int kt = 0; kt < 4; ++kt){
            int fi = (w*4+kt)*64 + lane;
            BQ[kt] = WpkQ[fi];
            BK[kt] = WpkK[fi];
            BV[kt] = WpkV[fi];
        }
        const int c0 = 16*w + nl;
        const float xq = bq[c0], xk = bk_[c0], xv = bv_[c0];
        short* wbuf = s_h1 + w*2048;          // wave-private 4KB (2 bufs x 2KB)
        const f32x4 zero = {0.f,0.f,0.f,0.f};

        for (int t = 0; t < 8; ++t){
            const int n = base + t;
            const int L = lane_counts[n];
            const float invL = 1.f / (float)L;

            unsigned ab = lds_lo(s_emb) + t*4096 + trofs;
            bf16x4 tr[8];
            #pragma unroll
            for (int kt = 0; kt < 4; ++kt){
                tr[2*kt]   = ds_tr(ab + kt*1024);
                tr[2*kt+1] = ds_tr(ab + kt*1024 + 512);
            }
            lgkm0();
            f32x4 q0=zero, k0=zero, v0=zero;
            #pragma unroll
            for (int kt = 0; kt < 4; ++kt){
                bf16x8 A = cat44(tr[2*kt], tr[2*kt+1]);
                q0 = MFMA16(A, BQ[kt], q0);
                k0 = MFMA16(A, BK[kt], k0);
                v0 = MFMA16(A, BV[kt], v0);
            }
            // q shorts [0,256) | k [256,512) | v [512,768)
            short* buf = wbuf + (t&1)*1024;
            *(uint2*)&buf[nl*16 + 4*kb] =
                make_uint2(pk2(q0[0]+xq, q0[1]+xq), pk2(q0[2]+xq, q0[3]+xq));
            *(uint2*)&buf[256 + nl*16 + 4*kb] =
                make_uint2(pk2(k0[0]+xk, k0[1]+xk), pk2(k0[2]+xk, k0[3]+xk));
            *(uint2*)&buf[512 + nl*16 + 4*kb] =
                make_uint2(pk2(v0[0]+xv, v0[1]+xv), pk2(v0[2]+xv, v0[3]+xv));
            lgkm0();

            const unsigned ba = lds_lo(buf);
            bf16x4 qf = ds_tr(ba + trofs);
            bf16x4 kf = ds_tr(ba + 512 + trofs);
            bf16x4 vf = *(const bf16x4*)&buf[512 + nl*16 + 4*kb];
            lgkm0();

            f32x4 st = MFMA16(cat40(kf), cat40(qf), zero);  // rows j=4kb+r, col i=nl
            // softmax over key rows j (no max-sub: |score| << 1 for this model scale)
            float pr[4], ps = 0.f;
            #pragma unroll
            for (int r = 0; r < 4; ++r){
                pr[r] = (4*kb+r < L) ? __expf(st[r]*0.25f) : 0.f;
                ps += pr[r];
            }
            ps += __shfl_xor(ps, 16);
            ps += __shfl_xor(ps, 32);
            float inv = 1.f/ps;
            union { bf16x8 v; unsigned u[4]; } P;
            P.u[0] = pk2(pr[0]*inv, pr[1]*inv);
            P.u[1] = pk2(pr[2]*inv, pr[3]*inv);
            P.u[2] = 0; P.u[3] = 0;
            f32x4 ctx = MFMA16(P.v, cat40(vf), zero);       // rows i=4kb+r, col d=nl
            float pm = 0.f;
            #pragma unroll
            for (int r = 0; r < 4; ++r) if (4*kb+r < L) pm += ctx[r];
            pm += __shfl_xor(pm, 16);
            pm += __shfl_xor(pm, 32);
            if (kb == 0)
                meanb[((n>>4)<<11) + c0*16 + (n&15)] = f2bf(pm * invL);
        }
    }
}

// ============ kernel 2: tail (Wo/phase/region -> F1 -> F2 -> heads), 32 TLS/block ============
__global__ __launch_bounds__(256, 2) void k2_tail(
    const float* __restrict__ phase_onehot, const float* __restrict__ elapsed,
    const int* __restrict__ region_ids, const float* __restrict__ region_table,
    const float* __restrict__ Wp1, const float* __restrict__ bp1, const float* __restrict__ bp2,
    const float* __restrict__ bo,
    const float* __restrict__ bf1, const float* __restrict__ bf2_,
    const float* __restrict__ Wm, const float* __restrict__ bm,
    const float* __restrict__ Wval, const float* __restrict__ bval,
    const float* __restrict__ log_std,
    const short* __restrict__ wpk, const short* __restrict__ meanb,
    float* __restrict__ out)
{
    const int tid  = threadIdx.x;
    const int w    = tid >> 6, lane = tid & 63;
    const int nl   = lane & 15, kb = lane >> 4;
    const int base = blockIdx.x << 5;   // 32 TLS

    __shared__ __align__(512) short s_mean[2*2048];   // 8 KB
    __shared__ __align__(512) short s_ph1[2*2048];    // 8 KB
    __shared__ __align__(512) short s_fused[2*4608];  // 18 KB
    __shared__ __align__(512) short s_hf[2*4096];     // 16 KB
    __shared__ float s_part[4][2][16][2];             // 1 KB

    const unsigned trofs = (unsigned)(kb*128 + nl*8);
    const bf16x8* WpkO  = (const bf16x8*)(wpk + 65536);
    const bf16x8* WpkP2 = (const bf16x8*)(wpk + 81920);
    const bf16x8* WpkF1 = (const bf16x8*)(wpk + 98304);
    const bf16x8* WpkF2 = (const bf16x8*)(wpk + 172032);

    // 1. copy mean chunk (already col-major-16 in global) -> LDS, linear
    {
        const uint4* src = (const uint4*)(meanb + base*128);
        uint4* dst = (uint4*)s_mean;
        dst[tid]       = src[tid];
        dst[256 + tid] = src[256 + tid];
    }
    // 2. phase hidden: thread -> TLS r = tid>>3, cols 16*(tid&7)..+16
    {
        const int r = tid >> 3, cb = tid & 7, n = base + r;
        const float p0 = phase_onehot[n*4+0], p1 = phase_onehot[n*4+1];
        const float p2 = phase_onehot[n*4+2], p3 = phase_onehot[n*4+3];
        const float ev = elapsed[n];
        #pragma unroll
        for (int jc = 0; jc < 16; ++jc){
            int c = cb*16 + jc;
            float a = fmaf(p0, Wp1[c], fmaf(p1, Wp1[128+c], fmaf(p2, Wp1[256+c],
                      fmaf(p3, Wp1[384+c], fmaf(ev, Wp1[512+c], bp1[c])))));
            s_ph1[(r>>4)*2048 + c*16 + (r&15)] = f2bf(fmaxf(a, 0.f));
        }
        // 3. region embedding -> fused cols [256,288)
        const int rid = region_ids[n];
        #pragma unroll
        for (int jc = 0; jc < 4; ++jc){
            int c = (tid&7)*4 + jc;
            s_fused[(r>>4)*4608 + (256+c)*16 + (r&15)] = f2bf(region_table[rid*32 + c]);
        }
    }
    __syncthreads();

    // 4. Wo (no relu) + Wp2 (relu): wave w owns nt {2w,2w+1}
    {
        bf16x8 BO[8], BP[8];
        #pragma unroll
        for (int nt2 = 0; nt2 < 2; ++nt2)
            #pragma unroll
            for (int kt = 0; kt < 4; ++kt){
                int fi = ((2*w+nt2)*4+kt)*64 + lane;
                BO[nt2*4+kt] = WpkO[fi];
                BP[nt2*4+kt] = WpkP2[fi];
            }
        const int c0 = 32*w + nl, c1 = c0 + 16;
        const float o0b = bo[c0], o1b = bo[c1];
        const float p0b = bp2[c0], p1b = bp2[c1];
        #pragma unroll
        for (int mt = 0; mt < 2; ++mt){
            unsigned am = lds_lo(s_mean) + mt*4096 + trofs;
            unsigned ap = lds_lo(s_ph1)  + mt*4096 + trofs;
            bf16x4 t[16];
            #pragma unroll
            for (int kt = 0; kt < 4; ++kt){
                t[2*kt]     = ds_tr(am + kt*1024);
                t[2*kt+1]   = ds_tr(am + kt*1024 + 512);
                t[8+2*kt]   = ds_tr(ap + kt*1024);
                t[9+2*kt]   = ds_tr(ap + kt*1024 + 512);
            }
            lgkm0();
            f32x4 o0={0.f,0.f,0.f,0.f}, o1=o0, p0=o0, p1=o0;
            #pragma unroll
            for (int kt = 0; kt < 4; ++kt){
                bf16x8 Am = cat44(t[2*kt],   t[2*kt+1]);
                bf16x8 Ap = cat44(t[8+2*kt], t[9+2*kt]);
                o0 = MFMA16(Am, BO[kt],   o0);
                o1 = MFMA16(Am, BO[4+kt], o1);
                p0 = MFMA16(Ap, BP[kt],   p0);
                p1 = MFMA16(Ap, BP[4+kt], p1);
            }
            short* fb = s_fused + mt*4608;
            *(uint2*)&fb[c0*16 + 4*kb] =
                make_uint2(pk2(o0[0]+o0b, o0[1]+o0b), pk2(o0[2]+o0b, o0[3]+o0b));
            *(uint2*)&fb[c1*16 + 4*kb] =
                make_uint2(pk2(o1[0]+o1b, o1[1]+o1b), pk2(o1[2]+o1b, o1[3]+o1b));
            *(uint2*)&fb[(128+c0)*16 + 4*kb] =
                make_uint2(pk2(fmaxf(p0[0]+p0b,0.f), fmaxf(p0[1]+p0b,0.f)),
                           pk2(fmaxf(p0[2]+p0b,0.f), fmaxf(p0[3]+p0b,0.f)));
            *(uint2*)&fb[(128+c1)*16 + 4*kb] =
                make_uint2(pk2(fmaxf(p1[0]+p1b,0.f), fmaxf(p1[1]+p1b,0.f)),
                           pk2(fmaxf(p1[2]+p1b,0.f), fmaxf(p1[3]+p1b,0.f)));
        }
    }
    __syncthreads();

    // 5. F1: hf = relu(fused @ Wf1 + bf1), K=288; wave w owns nt {4w..4w+3}
    {
        bf16x8 A[2][9];
        #pragma unroll
        for (int mt = 0; mt < 2; ++mt){
            unsigned ab = lds_lo(s_fused) + mt*9216 + trofs;
            bf16x4 t[18];
            #pragma unroll
            for (int kt = 0; kt < 9; ++kt){
                t[2*kt]   = ds_tr(ab + kt*1024);
                t[2*kt+1] = ds_tr(ab + kt*1024 + 512);
            }
            lgkm0();
            #pragma unroll
            for (int kt = 0; kt < 9; ++kt) A[mt][kt] = cat44(t[2*kt], t[2*kt+1]);
        }
        #pragma unroll
        for (int nt2 = 0; nt2 < 4; ++nt2){
            const int nt = 4*w + nt2;
            bf16x8 Bf[9];
            #pragma unroll
            for (int kt = 0; kt < 9; ++kt) Bf[kt] = WpkF1[(nt*9+kt)*64 + lane];
            f32x4 a0 = {0.f,0.f,0.f,0.f}, a1 = a0;
            #pragma unroll
            for (int kt = 0; kt < 9; ++kt){
                a0 = MFMA16(A[0][kt], Bf[kt], a0);
                a1 = MFMA16(A[1][kt], Bf[kt], a1);
            }
            const int c = nt*16 + nl;
            const float bb = bf1[c];
            *(uint2*)&s_hf[c*16 + 4*kb] =
                make_uint2(pk2(fmaxf(a0[0]+bb,0.f), fmaxf(a0[1]+bb,0.f)),
                           pk2(fmaxf(a0[2]+bb,0.f), fmaxf(a0[3]+bb,0.f)));
            *(uint2*)&s_hf[4096 + c*16 + 4*kb] =
                make_uint2(pk2(fmaxf(a1[0]+bb,0.f), fmaxf(a1[1]+bb,0.f)),
                           pk2(fmaxf(a1[2]+bb,0.f), fmaxf(a1[3]+bb,0.f)));
        }
    }
    __syncthreads();

    // 6. F2 + heads epilogue: wave w owns nt {4w..4w+3}
    {
        bf16x8 A[2][8];
        #pragma unroll
        for (int mt = 0; mt < 2; ++mt){
            unsigned ab = lds_lo(s_hf) + mt*8192 + trofs;
            bf16x4 t[16];
            #pragma unroll
            for (int kt = 0; kt < 8; ++kt){
                t[2*kt]   = ds_tr(ab + kt*1024);
                t[2*kt+1] = ds_tr(ab + kt*1024 + 512);
            }
            lgkm0();
            #pragma unroll
            for (int kt = 0; kt < 8; ++kt) A[mt][kt] = cat44(t[2*kt], t[2*kt+1]);
        }
        float sm0[4] = {0,0,0,0}, sv0[4] = {0,0,0,0};
        float sm1[4] = {0,0,0,0}, sv1[4] = {0,0,0,0};
        #pragma unroll
        for (int nt2 = 0; nt2 < 4; ++nt2){
            const int nt = 4*w + nt2;
            bf16x8 Bf[8];
            #pragma unroll
            for (int kt = 0; kt < 8; ++kt) Bf[kt] = WpkF2[(nt*8+kt)*64 + lane];
            f32x4 a0 = {0.f,0.f,0.f,0.f}, a1 = a0;
            #pragma unroll
            for (int kt = 0; kt < 8; ++kt){
                a0 = MFMA16(A[0][kt], Bf[kt], a0);
                a1 = MFMA16(A[1][kt], Bf[kt], a1);
            }
            const int c = nt*16 + nl;
            const float bb = bf2_[c], wm = Wm[c], wv = Wval[c];
            #pragma unroll
            for (int r = 0; r < 4; ++r){
                float h0 = fmaxf(a0[r]+bb, 0.f);
                float h1 = fmaxf(a1[r]+bb, 0.f);
                sm0[r] = fmaf(h0, wm, sm0[r]);  sv0[r] = fmaf(h0, wv, sv0[r]);
                sm1[r] = fmaf(h1, wm, sm1[r]);  sv1[r] = fmaf(h1, wv, sv1[r]);
            }
        }
        #pragma unroll
        for (int off = 1; off < 16; off <<= 1){
            #pragma unroll
            for (int r = 0; r < 4; ++r){
                sm0[r] += __shfl_xor(sm0[r], off);  sv0[r] += __shfl_xor(sv0[r], off);
                sm1[r] += __shfl_xor(sm1[r], off);  sv1[r] += __shfl_xor(sv1[r], off);
            }
        }
        if (nl == 0){
            #pragma unroll
            for (int r = 0; r < 4; ++r){
                s_part[w][0][4*kb+r][0] = sm0[r];  s_part[w][0][4*kb+r][1] = sv0[r];
                s_part[w][1][4*kb+r][0] = sm1[r];  s_part[w][1][4*kb+r][1] = sv1[r];
            }
        }
    }
    __syncthreads();

    // 7. finalize
    if (tid < 32){
        const int r = tid, n = base + r;
        float sm = bm[0], sv = bval[0];
        #pragma unroll
        for (int ww = 0; ww < 4; ++ww){
            sm += s_part[ww][r>>4][r&15][0];
            sv += s_part[ww][r>>4][r&15][1];
        }
        out[n]          = sm;
        out[NTLS + n]   = log_std[0];
        out[2*NTLS + n] = sv;
    }
}

extern "C" void kernel_launch(void* const* d_in, const int* in_sizes, int n_in,
                              void* d_out, int out_size, void* d_ws, size_t ws_size,
                              hipStream_t stream) {
    const float* queues       = (const float*)d_in[0];
    const float* waits        = (const float*)d_in[1];
    const float* phase_onehot = (const float*)d_in[2];
    const float* elapsed      = (const float*)d_in[3];
    const int*   lane_counts  = (const int*)d_in[4];
    const int*   region_ids   = (const int*)d_in[5];
    const float* W1  = (const float*)d_in[6];
    const float* b1  = (const float*)d_in[7];
    const float* W2  = (const float*)d_in[8];
    const float* b2  = (const float*)d_in[9];
    const float* Wq  = (const float*)d_in[10];
    const float* bq  = (const float*)d_in[11];
    const float* Wk  = (const float*)d_in[12];
    const float* bk  = (const float*)d_in[13];
    const float* Wv  = (const float*)d_in[14];
    const float* bv  = (const float*)d_in[15];
    const float* Wo  = (const float*)d_in[16];
    const float* bo  = (const float*)d_in[17];
    const float* Wp1 = (const float*)d_in[18];
    const float* bp1 = (const float*)d_in[19];
    const float* Wp2 = (const float*)d_in[20];
    const float* bp2 = (const float*)d_in[21];
    const float* region_table = (const float*)d_in[22];
    const float* Wf1 = (const float*)d_in[23];
    const float* bf1 = (const float*)d_in[24];
    const float* Wf2 = (const float*)d_in[25];
    const float* bf2 = (const float*)d_in[26];
    const float* Wm  = (const float*)d_in[27];
    const float* bm  = (const float*)d_in[28];
    const float* Wval = (const float*)d_in[29];
    const float* bval = (const float*)d_in[30];
    const float* log_std = (const float*)d_in[31];
    float* out = (float*)d_out;

    short* wpk   = (short*)d_ws;                          // 475136 B packed weights
    short* meanb = (short*)((char*)d_ws + 524288);        // 4 MB col-major-16 mean

    prepack<<<116, 256, 0, stream>>>(W2, Wq, Wk, Wv, Wo, Wp2, Wf1, Wf2, wpk);
    k1_lane<<<2048, 512, 0, stream>>>(
        queues, waits, elapsed, lane_counts,
        W1, b1, b2, bq, bk, bv, wpk, meanb);
    k2_tail<<<512, 256, 0, stream>>>(
        phase_onehot, elapsed, region_ids, region_table,
        Wp1, bp1, bp2, bo, bf1, bf2, Wm, bm, Wval, bval, log_std,
        wpk, meanb, out);
}

// Round 7
// 186.005 us; speedup vs baseline: 5.3692x; 1.0227x over previous
//
#include <hip/hip_runtime.h>
#include <hip/hip_bf16.h>
#include <stdint.h>

#define NTLS 16384

typedef float f32x4 __attribute__((ext_vector_type(4)));
typedef short bf16x8 __attribute__((ext_vector_type(8)));
typedef short bf16x4 __attribute__((ext_vector_type(4)));

// packed fp32->bf16 (RNE) via native instruction
__device__ __forceinline__ unsigned pk2(float a, float b){
    unsigned r;
    asm("v_cvt_pk_bf16_f32 %0, %1, %2" : "=v"(r) : "v"(a), "v"(b));
    return r;
}
__device__ __forceinline__ short f2bf(float x){
    return (short)(pk2(x, 0.f) & 0xffff);
}
__device__ __forceinline__ unsigned lds_lo(const void* p){
    return (unsigned)(size_t)p;
}
__device__ __forceinline__ bf16x4 ds_tr(unsigned addr){
    bf16x4 d;
    asm volatile("ds_read_b64_tr_b16 %0, %1" : "=v"(d) : "v"(addr) : "memory");
    return d;
}
__device__ __forceinline__ void lgkm0(){
    asm volatile("s_waitcnt lgkmcnt(0)" ::: "memory");
    __builtin_amdgcn_sched_barrier(0);
}
__device__ __forceinline__ bf16x8 cat44(bf16x4 lo, bf16x4 hi){
    bf16x8 r;
    r[0]=lo[0]; r[1]=lo[1]; r[2]=lo[2]; r[3]=lo[3];
    r[4]=hi[0]; r[5]=hi[1]; r[6]=hi[2]; r[7]=hi[3];
    return r;
}
__device__ __forceinline__ bf16x8 cat40(bf16x4 lo){
    bf16x8 r;
    r[0]=lo[0]; r[1]=lo[1]; r[2]=lo[2]; r[3]=lo[3];
    r[4]=0; r[5]=0; r[6]=0; r[7]=0;
    return r;
}
#define MFMA16(a,b,c) __builtin_amdgcn_mfma_f32_16x16x32_bf16((a),(b),(c),0,0,0)

// ---------------- weight prepack (verified): fp32 row-major -> bf16 frag-linear
__global__ __launch_bounds__(256) void prepack(
    const float* __restrict__ W2, const float* __restrict__ Wq,
    const float* __restrict__ Wk, const float* __restrict__ Wv,
    const float* __restrict__ Wo, const float* __restrict__ Wp2,
    const float* __restrict__ Wf1, const float* __restrict__ Wf2,
    short* __restrict__ out)
{
    int gid = blockIdx.x * 256 + threadIdx.x;      // 0..29695
    const float* src; short* dst; int K, Nn; int id = gid;
    if (id < 12288){
        int wsel = id >> 11; id &= 2047;
        const float* tab[6] = {W2, Wq, Wk, Wv, Wo, Wp2};
        src = tab[wsel]; dst = out + wsel * 16384; K = 128; Nn = 128;
    } else if (id < 21504){
        id -= 12288; src = Wf1; dst = out + 98304; K = 288; Nn = 256;
    } else {
        id -= 21504; src = Wf2; dst = out + 172032; K = 256; Nn = 256;
    }
    int lane = id & 63, f = id >> 6;
    int KT = K >> 5;
    int nt = f / KT, kt = f - nt * KT;
    int n  = nt * 16 + (lane & 15);
    int kb = kt * 32 + 4 * (lane >> 4);
    unsigned w0 = pk2(src[(kb+0)*Nn+n],  src[(kb+1)*Nn+n]);
    unsigned w1 = pk2(src[(kb+2)*Nn+n],  src[(kb+3)*Nn+n]);
    unsigned w2 = pk2(src[(kb+16)*Nn+n], src[(kb+17)*Nn+n]);
    unsigned w3 = pk2(src[(kb+18)*Nn+n], src[(kb+19)*Nn+n]);
    *(uint4*)&dst[(f*64+lane)*8] = make_uint4(w0,w1,w2,w3);
}

// ============ kernel 1: lane pipeline (round-4 verified structure + register pins) ============
__global__ __launch_bounds__(512, 4) void k1_lane(
    const float* __restrict__ queues, const float* __restrict__ waits,
    const float* __restrict__ elapsed, const int* __restrict__ lane_counts,
    const float* __restrict__ W1, const float* __restrict__ b1,
    const float* __restrict__ b2,
    const float* __restrict__ bq, const float* __restrict__ bk_, const float* __restrict__ bv_,
    const short* __restrict__ wpk,
    short* __restrict__ meanb)
{
    const int tid  = threadIdx.x;
    const int w    = tid >> 6, lane = tid & 63;
    const int nl   = lane & 15, kb = lane >> 4;
    const int base = blockIdx.x << 3;

    __shared__ __align__(512) short s_h1[8*2048];   // 32KB; stage C: wave-private qkv bufs
    __shared__ __align__(512) short s_emb[8*2048];  // 32KB

    const unsigned trofs = (unsigned)(kb*128 + nl*8);
    const bf16x8* Wpk2 = (const bf16x8*)(wpk);
    const bf16x8* WpkQ = (const bf16x8*)(wpk + 16384);
    const bf16x8* WpkK = (const bf16x8*)(wpk + 32768);
    const bf16x8* WpkV = (const bf16x8*)(wpk + 49152);

    // ---- stage A: wave w computes h1 for TLS w (all 128 cols, 16 rows)
    {
        const int n = base + w;
        const float ev = elapsed[n];
        float qv = queues[n*16 + nl];
        float wv = waits [n*16 + nl];
        float qm[4], wmv[4];
        #pragma unroll
        for (int r = 0; r < 4; ++r){
            qm[r]  = __shfl(qv, 4*kb + r, 16);
            wmv[r] = __shfl(wv, 4*kb + r, 16);
        }
        #pragma unroll
        for (int i = 0; i < 8; ++i){
            int c = nl + 16*i;
            float w0 = W1[c], w1 = W1[128+c], w2 = W1[256+c], bb = b1[c];
            float v0 = fmaxf(fmaf(qm[0], w0, fmaf(wmv[0], w1, fmaf(ev, w2, bb))), 0.f);
            float v1 = fmaxf(fmaf(qm[1], w0, fmaf(wmv[1], w1, fmaf(ev, w2, bb))), 0.f);
            float v2 = fmaxf(fmaf(qm[2], w0, fmaf(wmv[2], w1, fmaf(ev, w2, bb))), 0.f);
            float v3 = fmaxf(fmaf(qm[3], w0, fmaf(wmv[3], w1, fmaf(ev, w2, bb))), 0.f);
            *(uint2*)&s_h1[w*2048 + c*16 + 4*kb] = make_uint2(pk2(v0,v1), pk2(v2,v3));
        }
    }
    __syncthreads();

    // ---- stage B: emb = relu(h1 @ W2 + b2); wave w owns cols [16w,16w+16), loops 8 TLS
    {
        bf16x8 B2[4];
        #pragma unroll
        for (int kt = 0; kt < 4; ++kt) B2[kt] = Wpk2[(w*4+kt)*64 + lane];
        #pragma unroll
        for (int kt = 0; kt < 4; ++kt) asm volatile("" : "+v"(B2[kt]));   // pin: no remat
        const int c0 = 16*w + nl;
        const float bb0 = b2[c0];
        for (int t = 0; t < 8; ++t){
            unsigned ab = lds_lo(s_h1) + t*4096 + trofs;
            bf16x4 tr[8];
            #pragma unroll
            for (int kt = 0; kt < 4; ++kt){
                tr[2*kt]   = ds_tr(ab + kt*1024);
                tr[2*kt+1] = ds_tr(ab + kt*1024 + 512);
            }
            lgkm0();
            f32x4 a0 = {0.f,0.f,0.f,0.f};
            #pragma unroll
            for (int kt = 0; kt < 4; ++kt)
                a0 = MFMA16(cat44(tr[2*kt], tr[2*kt+1]), B2[kt], a0);
            *(uint2*)&s_emb[t*2048 + c0*16 + 4*kb] =
                make_uint2(pk2(fmaxf(a0[0]+bb0,0.f), fmaxf(a0[1]+bb0,0.f)),
                           pk2(fmaxf(a0[2]+bb0,0.f), fmaxf(a0[3]+bb0,0.f)));
        }
    }
    __syncthreads();   // all stage-B reads of s_h1 done -> safe to overlay qkv bufs

    // ---- stage C + attention: wave w owns head w (cols [16w,16w+16))
    {
        bf16x8 BQ[4], BK[4], BV[4];
        #pragma unroll
        for (int kt = 0; kt < 4; ++kt){
            int fi = (w*4+kt)*64 + lane;
            BQ[kt] = WpkQ[fi];
            BK[kt] = WpkK[fi];
            BV[kt] = WpkV[fi];
        }
        #pragma unroll
        for (int kt = 0; kt < 4; ++kt)
            asm volatile("" : "+v"(BQ[kt]), "+v"(BK[kt]), "+v"(BV[kt]));  // pin: no remat
        const int c0 = 16*w + nl;
        const float xq = bq[c0], xk = bk_[c0], xv = bv_[c0];
        short* wbuf = s_h1 + w*2048;          // wave-private 4KB (2 bufs x 2KB)
        const f32x4 zero = {0.f,0.f,0.f,0.f};

        for (int t = 0; t < 8; ++t){
            const int n = base + t;
            const int L = lane_counts[n];
            const float invL = 1.f / (float)L;

            unsigned ab = lds_lo(s_emb) + t*4096 + trofs;
            bf16x4 tr[8];
            #pragma unroll
            for (int kt = 0; kt < 4; ++kt){
                tr[2*kt]   = ds_tr(ab + kt*1024);
                tr[2*kt+1] = ds_tr(ab + kt*1024 + 512);
            }
            lgkm0();
            f32x4 q0=zero, k0=zero, v0=zero;
            #pragma unroll
            for (int kt = 0; kt < 4; ++kt){
                bf16x8 A = cat44(tr[2*kt], tr[2*kt+1]);
                q0 = MFMA16(A, BQ[kt], q0);
                k0 = MFMA16(A, BK[kt], k0);
                v0 = MFMA16(A, BV[kt], v0);
            }
            // q shorts [0,256) | k [256,512) | v [512,768)
            short* buf = wbuf + (t&1)*1024;
            *(uint2*)&buf[nl*16 + 4*kb] =
                make_uint2(pk2(q0[0]+xq, q0[1]+xq), pk2(q0[2]+xq, q0[3]+xq));
            *(uint2*)&buf[256 + nl*16 + 4*kb] =
                make_uint2(pk2(k0[0]+xk, k0[1]+xk), pk2(k0[2]+xk, k0[3]+xk));
            *(uint2*)&buf[512 + nl*16 + 4*kb] =
                make_uint2(pk2(v0[0]+xv, v0[1]+xv), pk2(v0[2]+xv, v0[3]+xv));
            lgkm0();

            const unsigned ba = lds_lo(buf);
            bf16x4 qf = ds_tr(ba + trofs);
            bf16x4 kf = ds_tr(ba + 512 + trofs);
            bf16x4 vf = *(const bf16x4*)&buf[512 + nl*16 + 4*kb];
            lgkm0();

            f32x4 st = MFMA16(cat40(kf), cat40(qf), zero);  // rows j=4kb+r, col i=nl
            // softmax over key rows j (no max-sub: |score| << 1 for this model scale)
            float pr[4], ps = 0.f;
            #pragma unroll
            for (int r = 0; r < 4; ++r){
                pr[r] = (4*kb+r < L) ? __expf(st[r]*0.25f) : 0.f;
                ps += pr[r];
            }
            ps += __shfl_xor(ps, 16);
            ps += __shfl_xor(ps, 32);
            float inv = 1.f/ps;
            union { bf16x8 v; unsigned u[4]; } P;
            P.u[0] = pk2(pr[0]*inv, pr[1]*inv);
            P.u[1] = pk2(pr[2]*inv, pr[3]*inv);
            P.u[2] = 0; P.u[3] = 0;
            f32x4 ctx = MFMA16(P.v, cat40(vf), zero);       // rows i=4kb+r, col d=nl
            float pm = 0.f;
            #pragma unroll
            for (int r = 0; r < 4; ++r) if (4*kb+r < L) pm += ctx[r];
            pm += __shfl_xor(pm, 16);
            pm += __shfl_xor(pm, 32);
            if (kb == 0)
                meanb[((n>>4)<<11) + c0*16 + (n&15)] = f2bf(pm * invL);
        }
    }
}

// ============ kernel 2: tail (round-4 verified version), 32 TLS/block, 4 waves ============
__global__ __launch_bounds__(256, 2) void k2_tail(
    const float* __restrict__ phase_onehot, const float* __restrict__ elapsed,
    const int* __restrict__ region_ids, const float* __restrict__ region_table,
    const float* __restrict__ Wp1, const float* __restrict__ bp1, const float* __restrict__ bp2,
    const float* __restrict__ bo,
    const float* __restrict__ bf1, const float* __restrict__ bf2_,
    const float* __restrict__ Wm, const float* __restrict__ bm,
    const float* __restrict__ Wval, const float* __restrict__ bval,
    const float* __restrict__ log_std,
    const short* __restrict__ wpk, const short* __restrict__ meanb,
    float* __restrict__ out)
{
    const int tid  = threadIdx.x;
    const int w    = tid >> 6, lane = tid & 63;
    const int nl   = lane & 15, kb = lane >> 4;
    const int base = blockIdx.x << 5;   // 32 TLS

    __shared__ __align__(512) short s_mean[2*2048];   // 8 KB
    __shared__ __align__(512) short s_ph1[2*2048];    // 8 KB
    __shared__ __align__(512) short s_fused[2*4608];  // 18 KB
    __shared__ __align__(512) short s_hf[2*4096];     // 16 KB
    __shared__ float s_part[4][2][16][2];             // 1 KB

    const unsigned trofs = (unsigned)(kb*128 + nl*8);
    const bf16x8* WpkO  = (const bf16x8*)(wpk + 65536);
    const bf16x8* WpkP2 = (const bf16x8*)(wpk + 81920);
    const bf16x8* WpkF1 = (const bf16x8*)(wpk + 98304);
    const bf16x8* WpkF2 = (const bf16x8*)(wpk + 172032);

    // 1. copy mean chunk (already col-major-16 in global) -> LDS, linear
    {
        const uint4* src = (const uint4*)(meanb + base*128);
        uint4* dst = (uint4*)s_mean;
        dst[tid]       = src[tid];
        dst[256 + tid] = src[256 + tid];
    }
    // 2. phase hidden: thread -> TLS r = tid>>3, cols 16*(tid&7)..+16
    {
        const int r = tid >> 3, cb = tid & 7, n = base + r;
        const float p0 = phase_onehot[n*4+0], p1 = phase_onehot[n*4+1];
        const float p2 = phase_onehot[n*4+2], p3 = phase_onehot[n*4+3];
        const float ev = elapsed[n];
        #pragma unroll
        for (int jc = 0; jc < 16; ++jc){
            int c = cb*16 + jc;
            float a = fmaf(p0, Wp1[c], fmaf(p1, Wp1[128+c], fmaf(p2, Wp1[256+c],
                      fmaf(p3, Wp1[384+c], fmaf(ev, Wp1[512+c], bp1[c])))));
            s_ph1[(r>>4)*2048 + c*16 + (r&15)] = f2bf(fmaxf(a, 0.f));
        }
        // 3. region embedding -> fused cols [256,288)
        const int rid = region_ids[n];
        #pragma unroll
        for (int jc = 0; jc < 4; ++jc){
            int c = (tid&7)*4 + jc;
            s_fused[(r>>4)*4608 + (256+c)*16 + (r&15)] = f2bf(region_table[rid*32 + c]);
        }
    }
    __syncthreads();

    // 4. Wo (no relu) + Wp2 (relu): wave w owns nt {2w,2w+1}
    {
        bf16x8 BO[8], BP[8];
        #pragma unroll
        for (int nt2 = 0; nt2 < 2; ++nt2)
            #pragma unroll
            for (int kt = 0; kt < 4; ++kt){
                int fi = ((2*w+nt2)*4+kt)*64 + lane;
                BO[nt2*4+kt] = WpkO[fi];
                BP[nt2*4+kt] = WpkP2[fi];
            }
        const int c0 = 32*w + nl, c1 = c0 + 16;
        const float o0b = bo[c0], o1b = bo[c1];
        const float p0b = bp2[c0], p1b = bp2[c1];
        #pragma unroll
        for (int mt = 0; mt < 2; ++mt){
            unsigned am = lds_lo(s_mean) + mt*4096 + trofs;
            unsigned ap = lds_lo(s_ph1)  + mt*4096 + trofs;
            bf16x4 t[16];
            #pragma unroll
            for (int kt = 0; kt < 4; ++kt){
                t[2*kt]     = ds_tr(am + kt*1024);
                t[2*kt+1]   = ds_tr(am + kt*1024 + 512);
                t[8+2*kt]   = ds_tr(ap + kt*1024);
                t[9+2*kt]   = ds_tr(ap + kt*1024 + 512);
            }
            lgkm0();
            f32x4 o0={0.f,0.f,0.f,0.f}, o1=o0, p0=o0, p1=o0;
            #pragma unroll
            for (int kt = 0; kt < 4; ++kt){
                bf16x8 Am = cat44(t[2*kt],   t[2*kt+1]);
                bf16x8 Ap = cat44(t[8+2*kt], t[9+2*kt]);
                o0 = MFMA16(Am, BO[kt],   o0);
                o1 = MFMA16(Am, BO[4+kt], o1);
                p0 = MFMA16(Ap, BP[kt],   p0);
                p1 = MFMA16(Ap, BP[4+kt], p1);
            }
            short* fb = s_fused + mt*4608;
            *(uint2*)&fb[c0*16 + 4*kb] =
                make_uint2(pk2(o0[0]+o0b, o0[1]+o0b), pk2(o0[2]+o0b, o0[3]+o0b));
            *(uint2*)&fb[c1*16 + 4*kb] =
                make_uint2(pk2(o1[0]+o1b, o1[1]+o1b), pk2(o1[2]+o1b, o1[3]+o1b));
            *(uint2*)&fb[(128+c0)*16 + 4*kb] =
                make_uint2(pk2(fmaxf(p0[0]+p0b,0.f), fmaxf(p0[1]+p0b,0.f)),
                           pk2(fmaxf(p0[2]+p0b,0.f), fmaxf(p0[3]+p0b,0.f)));
            *(uint2*)&fb[(128+c1)*16 + 4*kb] =
                make_uint2(pk2(fmaxf(p1[0]+p1b,0.f), fmaxf(p1[1]+p1b,0.f)),
                           pk2(fmaxf(p1[2]+p1b,0.f), fmaxf(p1[3]+p1b,0.f)));
        }
    }
    __syncthreads();

    // 5. F1: hf = relu(fused @ Wf1 + bf1), K=288; wave w owns nt {4w..4w+3}
    {
        bf16x8 A[2][9];
        #pragma unroll
        for (int mt = 0; mt < 2; ++mt){
            unsigned ab = lds_lo(s_fused) + mt*9216 + trofs;
            bf16x4 t[18];
            #pragma unroll
            for (int kt = 0; kt < 9; ++kt){
                t[2*kt]   = ds_tr(ab + kt*1024);
                t[2*kt+1] = ds_tr(ab + kt*1024 + 512);
            }
            lgkm0();
            #pragma unroll
            for (int kt = 0; kt < 9; ++kt) A[mt][kt] = cat44(t[2*kt], t[2*kt+1]);
        }
        #pragma unroll
        for (int nt2 = 0; nt2 < 4; ++nt2){
            const int nt = 4*w + nt2;
            bf16x8 Bf[9];
            #pragma unroll
            for (int kt = 0; kt < 9; ++kt) Bf[kt] = WpkF1[(nt*9+kt)*64 + lane];
            f32x4 a0 = {0.f,0.f,0.f,0.f}, a1 = a0;
            #pragma unroll
            for (int kt = 0; kt < 9; ++kt){
                a0 = MFMA16(A[0][kt], Bf[kt], a0);
                a1 = MFMA16(A[1][kt], Bf[kt], a1);
            }
            const int c = nt*16 + nl;
            const float bb = bf1[c];
            *(uint2*)&s_hf[c*16 + 4*kb] =
                make_uint2(pk2(fmaxf(a0[0]+bb,0.f), fmaxf(a0[1]+bb,0.f)),
                           pk2(fmaxf(a0[2]+bb,0.f), fmaxf(a0[3]+bb,0.f)));
            *(uint2*)&s_hf[4096 + c*16 + 4*kb] =
                make_uint2(pk2(fmaxf(a1[0]+bb,0.f), fmaxf(a1[1]+bb,0.f)),
                           pk2(fmaxf(a1[2]+bb,0.f), fmaxf(a1[3]+bb,0.f)));
        }
    }
    __syncthreads();

    // 6. F2 + heads epilogue: wave w owns nt {4w..4w+3}
    {
        bf16x8 A[2][8];
        #pragma unroll
        for (int mt = 0; mt < 2; ++mt){
            unsigned ab = lds_lo(s_hf) + mt*8192 + trofs;
            bf16x4 t[16];
            #pragma unroll
            for (int kt = 0; kt < 8; ++kt){
                t[2*kt]   = ds_tr(ab + kt*1024);
                t[2*kt+1] = ds_tr(ab + kt*1024 + 512);
            }
            lgkm0();
            #pragma unroll
            for (int kt = 0; kt < 8; ++kt) A[mt][kt] = cat44(t[2*kt], t[2*kt+1]);
        }
        float sm0[4] = {0,0,0,0}, sv0[4] = {0,0,0,0};
        float sm1[4] = {0,0,0,0}, sv1[4] = {0,0,0,0};
        #pragma unroll
        for (int nt2 = 0; nt2 < 4; ++nt2){
            const int nt = 4*w + nt2;
            bf16x8 Bf[8];
            #pragma unroll
            for (int kt = 0; kt < 8; ++kt) Bf[kt] = WpkF2[(nt*8+kt)*64 + lane];
            f32x4 a0 = {0.f,0.f,0.f,0.f}, a1 = a0;
            #pragma unroll
            for (int kt = 0; kt < 8; ++kt){
                a0 = MFMA16(A[0][kt], Bf[kt], a0);
                a1 = MFMA16(A[1][kt], Bf[kt], a1);
            }
            const int c = nt*16 + nl;
            const float bb = bf2_[c], wm = Wm[c], wv = Wval[c];
            #pragma unroll
            for (int r = 0; r < 4; ++r){
                float h0 = fmaxf(a0[r]+bb, 0.f);
                float h1 = fmaxf(a1[r]+bb, 0.f);
                sm0[r] = fmaf(h0, wm, sm0[r]);  sv0[r] = fmaf(h0, wv, sv0[r]);
                sm1[r] = fmaf(h1, wm, sm1[r]);  sv1[r] = fmaf(h1, wv, sv1[r]);
            }
        }
        #pragma unroll
        for (int off = 1; off < 16; off <<= 1){
            #pragma unroll
            for (int r = 0; r < 4; ++r){
                sm0[r] += __shfl_xor(sm0[r], off);  sv0[r] += __shfl_xor(sv0[r], off);
                sm1[r] += __shfl_xor(sm1[r], off);  sv1[r] += __shfl_xor(sv1[r], off);
            }
        }
        if (nl == 0){
            #pragma unroll
            for (int r = 0; r < 4; ++r){
                s_part[w][0][4*kb+r][0] = sm0[r];  s_part[w][0][4*kb+r][1] = sv0[r];
                s_part[w][1][4*kb+r][0] = sm1[r];  s_part[w][1][4*kb+r][1] = sv1[r];
            }
        }
    }
    __syncthreads();

    // 7. finalize
    if (tid < 32){
        const int r = tid, n = base + r;
        float sm = bm[0], sv = bval[0];
        #pragma unroll
        for (int ww = 0; ww < 4; ++ww){
            sm += s_part[ww][r>>4][r&15][0];
            sv += s_part[ww][r>>4][r&15][1];
        }
        out[n]          = sm;
        out[NTLS + n]   = log_std[0];
        out[2*NTLS + n] = sv;
    }
}

extern "C" void kernel_launch(void* const* d_in, const int* in_sizes, int n_in,
                              void* d_out, int out_size, void* d_ws, size_t ws_size,
                              hipStream_t stream) {
    const float* queues       = (const float*)d_in[0];
    const float* waits        = (const float*)d_in[1];
    const float* phase_onehot = (const float*)d_in[2];
    const float* elapsed      = (const float*)d_in[3];
    const int*   lane_counts  = (const int*)d_in[4];
    const int*   region_ids   = (const int*)d_in[5];
    const float* W1  = (const float*)d_in[6];
    const float* b1  = (const float*)d_in[7];
    const float* W2  = (const float*)d_in[8];
    const float* b2  = (const float*)d_in[9];
    const float* Wq  = (const float*)d_in[10];
    const float* bq  = (const float*)d_in[11];
    const float* Wk  = (const float*)d_in[12];
    const float* bk  = (const float*)d_in[13];
    const float* Wv  = (const float*)d_in[14];
    const float* bv  = (const float*)d_in[15];
    const float* Wo  = (const float*)d_in[16];
    const float* bo  = (const float*)d_in[17];
    const float* Wp1 = (const float*)d_in[18];
    const float* bp1 = (const float*)d_in[19];
    const float* Wp2 = (const float*)d_in[20];
    const float* bp2 = (const float*)d_in[21];
    const float* region_table = (const float*)d_in[22];
    const float* Wf1 = (const float*)d_in[23];
    const float* bf1 = (const float*)d_in[24];
    const float* Wf2 = (const float*)d_in[25];
    const float* bf2 = (const float*)d_in[26];
    const float* Wm  = (const float*)d_in[27];
    const float* bm  = (const float*)d_in[28];
    const float* Wval = (const float*)d_in[29];
    const float* bval = (const float*)d_in[30];
    const float* log_std = (const float*)d_in[31];
    float* out = (float*)d_out;

    short* wpk   = (short*)d_ws;                          // 475136 B packed weights
    short* meanb = (short*)((char*)d_ws + 524288);        // 4 MB col-major-16 mean

    prepack<<<116, 256, 0, stream>>>(W2, Wq, Wk, Wv, Wo, Wp2, Wf1, Wf2, wpk);
    k1_lane<<<2048, 512, 0, stream>>>(
        queues, waits, elapsed, lane_counts,
        W1, b1, b2, bq, bk, bv, wpk, meanb);
    k2_tail<<<512, 256, 0, stream>>>(
        phase_onehot, elapsed, region_ids, region_table,
        Wp1, bp1, bp2, bo, bf1, bf2, Wm, bm, Wval, bval, log_std,
        wpk, meanb, out);
}